// Round 18
// baseline (803.627 us; speedup 1.0000x reference)
//
#include <hip/hip_runtime.h>
#include <cstdint>
#include <cstddef>

#define ND 8000
#define NL 16000
#define NE 60000
#define NM 50000

#define BM 64
#define BN 64
#define BK 16

typedef __attribute__((ext_vector_type(8))) short bf16x8;
typedef __attribute__((ext_vector_type(4))) float f32x4;
typedef __attribute__((ext_vector_type(8))) unsigned int u32x8;

__device__ __forceinline__ unsigned short f2bf(float x) {
    unsigned int u = __float_as_uint(x);
    unsigned int r = (u + 0x7FFFu + ((u >> 16) & 1u)) >> 16;
    return (unsigned short)r;
}
__device__ __forceinline__ float bf2f(unsigned short b) {
    return __uint_as_float(((unsigned int)b) << 16);
}
__device__ __forceinline__ float lrelu(float x) {
    return x >= 0.f ? x : 0.2f * x;
}

// ---------------- merged layer-3 GEMM: zs3d = hd @ W[0], zs3l = hl @ W[1] --------------
__global__ __launch_bounds__(256) void gemm3_kernel(
    const float* __restrict__ hd, const float* __restrict__ hl,
    const float* __restrict__ W,   // [2,128,512]
    float* __restrict__ zs3d, float* __restrict__ zs3l)
{
    __shared__ float As[BK][BM + 4];
    __shared__ float Bs[BK][BN + 4];
    int mt = blockIdx.y;
    const float* A; const float* B; float* Cm;
    if (mt < 125) { A = hd; B = W; Cm = zs3d; }
    else { mt -= 125; A = hl; B = W + 128 * 512; Cm = zs3l; }
    const int tid = threadIdx.x;
    const int tx = tid & 15, ty = tid >> 4;
    const int bm = mt * BM, bn = blockIdx.x * BN;
    float acc[4][4] = {};
    for (int k0 = 0; k0 < 128; k0 += BK) {
#pragma unroll
        for (int i = 0; i < 4; ++i) {
            int idx = tid + i * 256;
            int ml = idx >> 4, kl = idx & 15;
            As[kl][ml] = A[(size_t)(bm + ml) * 128 + k0 + kl];
        }
#pragma unroll
        for (int i = 0; i < 4; ++i) {
            int idx = tid + i * 256;
            int kl = idx >> 6, nl = idx & 63;
            Bs[kl][nl] = B[(size_t)(k0 + kl) * 512 + bn + nl];
        }
        __syncthreads();
#pragma unroll
        for (int k = 0; k < BK; ++k) {
            float4 av = *(const float4*)&As[k][ty * 4];
            float4 bv = *(const float4*)&Bs[k][tx * 4];
            float a4[4] = {av.x, av.y, av.z, av.w};
            float b4[4] = {bv.x, bv.y, bv.z, bv.w};
#pragma unroll
            for (int i = 0; i < 4; ++i)
#pragma unroll
                for (int j = 0; j < 4; ++j)
                    acc[i][j] += a4[i] * b4[j];
        }
        __syncthreads();
    }
#pragma unroll
    for (int i = 0; i < 4; ++i) {
        int gm = bm + ty * 4 + i;
        int gn0 = bn + tx * 4;
        float4 v;
        float* vp = &v.x;
#pragma unroll
        for (int j = 0; j < 4; ++j) vp[j] = acc[i][j];
        *(float4*)&Cm[(size_t)gm * 512 + gn0] = v;
    }
}

// ---------------- fused input linears, 32-row tiles, register double-buffer ------------
__global__ __launch_bounds__(256) void inlin_kernel(
    const float* __restrict__ x_d, const float* __restrict__ x_l,
    const float* __restrict__ wd, const float* __restrict__ wl,
    const float* __restrict__ bd, const float* __restrict__ bl,
    const float* __restrict__ embd, const float* __restrict__ embl,
    const int* __restrict__ nidd, const int* __restrict__ nidl,
    float* __restrict__ hd, float* __restrict__ hl)
{
    __shared__ float As[BK][32 + 4];
    __shared__ float Bs[BK][BN + 4];
    int mt = blockIdx.y;
    const float* A; const float* B; const float* bias; const float* emb;
    const int* nid; float* out;
    int K;
    if (mt < 250) {
        A = x_d; B = wd; bias = bd; emb = embd; nid = nidd; out = hd; K = 412;
    } else {
        mt -= 250;
        A = x_l; B = wl; bias = bl; emb = embl; nid = nidl; out = hl; K = 240;
    }
    const int tid = threadIdx.x;
    const int tx = tid & 15, ty = tid >> 4;
    const int bm = mt * 32, bn = blockIdx.x * BN;

    const int aml0 = tid >> 4, akl0 = tid & 15;
    const int aml1 = (tid + 256) >> 4, akl1 = tid & 15;
    const int bkl = tid >> 6, bnl = tid & 63;

    float pa[2], pb[4];
    {
        int gk0 = akl0, gk1 = akl1;
        pa[0] = (gk0 < K) ? A[(size_t)(bm + aml0) * K + gk0] : 0.f;
        pa[1] = (gk1 < K) ? A[(size_t)(bm + aml1) * K + gk1] : 0.f;
#pragma unroll
        for (int i = 0; i < 4; ++i) {
            int gk = bkl + i * 4;
            pb[i] = (gk < K) ? B[(size_t)gk * 128 + bn + bnl] : 0.f;
        }
    }

    float acc[2][4] = {};
    for (int k0 = 0; k0 < K; k0 += BK) {
        As[akl0][aml0] = pa[0];
        As[akl1][aml1] = pa[1];
#pragma unroll
        for (int i = 0; i < 4; ++i)
            Bs[bkl + i * 4][bnl] = pb[i];
        __syncthreads();
        int kn = k0 + BK;
        if (kn < K) {
            int gk0 = kn + akl0, gk1 = kn + akl1;
            pa[0] = (gk0 < K) ? A[(size_t)(bm + aml0) * K + gk0] : 0.f;
            pa[1] = (gk1 < K) ? A[(size_t)(bm + aml1) * K + gk1] : 0.f;
#pragma unroll
            for (int i = 0; i < 4; ++i) {
                int gk = kn + bkl + i * 4;
                pb[i] = (gk < K) ? B[(size_t)gk * 128 + bn + bnl] : 0.f;
            }
        }
#pragma unroll
        for (int k = 0; k < BK; ++k) {
            float a0 = As[k][ty * 2];
            float a1 = As[k][ty * 2 + 1];
            float4 bv = *(const float4*)&Bs[k][tx * 4];
            float b4[4] = {bv.x, bv.y, bv.z, bv.w};
#pragma unroll
            for (int j = 0; j < 4; ++j) {
                acc[0][j] += a0 * b4[j];
                acc[1][j] += a1 * b4[j];
            }
        }
        __syncthreads();
    }
#pragma unroll
    for (int i = 0; i < 2; ++i) {
        int gm = bm + ty * 2 + i;
        int gn0 = bn + tx * 4;
        const float* ep = emb + (size_t)nid[gm] * 128 + gn0;
        float4 v;
        float* vp = &v.x;
#pragma unroll
        for (int j = 0; j < 4; ++j)
            vp[j] = acc[i][j] + bias[gn0 + j] + ep[j];
        *(float4*)&out[(size_t)gm * 128 + gn0] = v;
    }
}

// ---------------- W transpose + split-bf16 into MFMA-fragment tiling, BOTH layers ------
__global__ void wt2_kernel(const float* __restrict__ W0, const float* __restrict__ W1,
                           unsigned short* __restrict__ WtH, unsigned short* __restrict__ WtL)
{
    int gid = blockIdx.x * 256 + threadIdx.x;
    if (gid >= 2 * 2 * 128 * 2048) return;
    int l = gid >> 19;
    int rem0 = gid & 524287;
    int dir = rem0 >> 18;
    int rem = rem0 & 262143;
    int k = rem >> 11, n = rem & 2047;
    const float* W = l ? W1 : W0;
    float v = W[(size_t)dir * 262144 + (size_t)k * 2048 + n];
    unsigned short hb = f2bf(v);
    unsigned short lb = f2bf(v - bf2f(hb));
    int u = n >> 4;
    int lane = (n & 15) + 16 * ((k >> 3) & 3);
    size_t o = (size_t)l * 524288 + (size_t)dir * 262144 +
               ((size_t)u * 4 + (k >> 5)) * 512 + lane * 8 + (k & 7);
    WtH[o] = hb;
    WtL[o] = lb;
}

// ---------------- fused per-head projection + bias + relu + HEAD-MEAN (layers 1-2) ----
// 8-way column split, XCD-aware: i = g*64 + cb*8 + r -> mt = g*8 + r, cb = (i>>3)&7.
// All 8 blocks sharing m-tile mt have the same i%8 -> same XCD -> A slice from L2.
// Each wave: 16 rows x 16 cols (one ctl tile). grid = ceil(mtiles/8)*64.
__global__ __launch_bounds__(256) void gemm2r_kernel(
    const unsigned int* __restrict__ haggP,
    const unsigned short* __restrict__ WtH, const unsigned short* __restrict__ WtL,
    const float* __restrict__ bias, float* __restrict__ out, int M)
{
    const int wave = threadIdx.x >> 6;
    const int lane = threadIdx.x & 63;
    const int i = blockIdx.x;
    const int cb = (i >> 3) & 7;             // column eighth (0..7)
    const int mt = (i >> 6) * 8 + (i & 7);   // m-tile
    if (mt >= (M >> 6)) return;
    const int m0 = mt * 64 + wave * 16;
    const int t = m0 >> 4;
    const int row = lane & 15;
    const int quad = lane >> 4;

    f32x4 mean = {};

    for (int h = 0; h < 16; ++h) {
        float bv = bias[h * 128 + cb * 16 + row];
        f32x4 accH = (f32x4){bv, bv, bv, bv};
        f32x4 accL = (f32x4){0.f, 0.f, 0.f, 0.f};
        const int u = h * 8 + cb;
#pragma unroll
        for (int kc = 0; kc < 4; ++kc) {
            const size_t aoff = (((size_t)t * 16 + h) * 4 + kc) * 512 + lane * 8;
            u32x8 p = *(const u32x8*)(haggP + aoff);
            bf16x8 aH, aL;
#pragma unroll
            for (int ii = 0; ii < 8; ++ii) {
                aH[ii] = (short)(p[ii] & 0xffffu);
                aL[ii] = (short)(p[ii] >> 16);
            }
            const size_t boff = ((size_t)u * 4 + kc) * 512 + lane * 8;
            bf16x8 bH = *(const bf16x8*)(WtH + boff);
            bf16x8 bL = *(const bf16x8*)(WtL + boff);
            accH = __builtin_amdgcn_mfma_f32_16x16x32_bf16(aH, bH, accH, 0, 0, 0);
            accL = __builtin_amdgcn_mfma_f32_16x16x32_bf16(aH, bL, accL, 0, 0, 0);
            accL = __builtin_amdgcn_mfma_f32_16x16x32_bf16(aL, bH, accL, 0, 0, 0);
        }
#pragma unroll
        for (int r = 0; r < 4; ++r)
            mean[r] += fmaxf(accH[r] + accL[r], 0.f);
    }

    const int c = cb * 16 + row;
#pragma unroll
    for (int r = 0; r < 4; ++r) {
        int gm = m0 + quad * 4 + r;
        out[(size_t)gm * 128 + c] = mean[r] * (1.f / 16.f);
    }
}

// ---------------- fold for ALL 3 layers ------------------------------------------------
__global__ void fold3_kernel(
    const float* __restrict__ Ws1, const float* __restrict__ Wd1,
    const float* __restrict__ as1, const float* __restrict__ ad1,
    const float* __restrict__ Ws2, const float* __restrict__ Wd2,
    const float* __restrict__ as2, const float* __restrict__ ad2,
    const float* __restrict__ Ws3, const float* __restrict__ Wd3,
    const float* __restrict__ as3, const float* __restrict__ ad3,
    float* __restrict__ fw3)
{
    int gid = blockIdx.x * blockDim.x + threadIdx.x;
    if (gid >= 3 * 4 * 128 * 16) return;
    int l = gid / 8192, rem1 = gid % 8192;
    int f = rem1 / 2048, rem = rem1 % 2048;
    int k = rem >> 4, h = rem & 15;
    int Ntot = (l == 2) ? 512 : 2048;
    int C = Ntot >> 4;
    const float* W;
    const float* a;
    if (l == 0) { W = (f & 1) ? Wd1 : Ws1; a = (f & 1) ? ad1 : as1; }
    else if (l == 1) { W = (f & 1) ? Wd2 : Ws2; a = (f & 1) ? ad2 : as2; }
    else { W = (f & 1) ? Wd3 : Ws3; a = (f & 1) ? ad3 : as3; }
    if (f >= 2) { W += 128 * Ntot; a += 16 * C; }
    float s = 0.f;
    for (int c = 0; c < C; ++c) s += W[(size_t)k * Ntot + h * C + c] * a[h * C + c];
    fw3[gid] = s;
}

// ---------------- score2both: all four folded scores of a layer ------------------------
__global__ __launch_bounds__(256) void score2both_kernel(
    const float* __restrict__ Hd, const float* __restrict__ Hl,
    const float* __restrict__ fw,
    float* __restrict__ ssb0, float* __restrict__ sdb1,
    float* __restrict__ sdb0, float* __restrict__ ssb1)
{
    __shared__ float hs[16 * 128];
    __shared__ float wa[128 * 16];
    __shared__ float wb[128 * 16];
    int b = blockIdx.x;
    const float* Hf; const float* WfA; const float* WfB;
    float* outA; float* outB; int n0;
    if (b < ND / 16) {
        Hf = Hd; WfA = fw; WfB = fw + 3 * 2048; outA = ssb0; outB = sdb1; n0 = b * 16;
    } else {
        Hf = Hl; WfA = fw + 1 * 2048; WfB = fw + 2 * 2048; outA = sdb0; outB = ssb1;
        n0 = (b - ND / 16) * 16;
    }
    int tid = threadIdx.x;
#pragma unroll
    for (int i = 0; i < 8; ++i) {
        int idx = tid + i * 256;
        int nl = idx >> 7, k = idx & 127;
        hs[idx] = Hf[(size_t)(n0 + nl) * 128 + k];
        wa[idx] = WfA[idx];
        wb[idx] = WfB[idx];
    }
    __syncthreads();
    int nl = tid >> 4, h = tid & 15;
    float sa = 0.f, sb = 0.f;
    for (int k = 0; k < 128; ++k) {
        float hv = hs[nl * 128 + k];
        sa += hv * wa[k * 16 + h];
        sb += hv * wb[k * 16 + h];
    }
    int gn = n0 + nl;
    outA[gn * 16 + h] = sa;
    outB[gn * 16 + h] = sb;
}

// ---------------- per-(dst,head) online softmax max/sum, logits inline -----------------
__global__ void ms_kernel(
    const int* __restrict__ esrc, const int* __restrict__ edst,
    const float* __restrict__ ssb0, const float* __restrict__ sdb0,
    const float* __restrict__ ssb1, const float* __restrict__ sdb1,
    const int* __restrict__ offl, const int* __restrict__ csrl, float* __restrict__ msl,
    const int* __restrict__ offd, const int* __restrict__ csrd, float* __restrict__ msd)
{
    int t = blockIdx.x * 256 + threadIdx.x;
    const int* off; const int* csr; const int* srcidx;
    const float* ss; float sdv; float* ms; int d, h;
    if (t < NL * 16) {
        d = t >> 4; h = t & 15;
        off = offl; csr = csrl; srcidx = esrc; ss = ssb0;
        sdv = sdb0[d * 16 + h]; ms = msl;
    } else {
        t -= NL * 16;
        if (t >= ND * 16) return;
        d = t >> 4; h = t & 15;
        off = offd; csr = csrd; srcidx = edst; ss = ssb1;
        sdv = sdb1[d * 16 + h]; ms = msd;
    }
    int e0 = off[d], e1 = off[d + 1];
    float m = -1e30f, s = 0.f;
    for (int e = e0; e < e1; ++e) {
        int sn = srcidx[csr[e]];
        float a = lrelu(ss[sn * 16 + h] + sdv);
        if (a > m) { s = s * __expf(m - a) + 1.f; m = a; }
        else s += __expf(a - m);
    }
    ms[d * 32 + h] = m;
    ms[d * 32 + 16 + h] = s + 1e-16f;
}

// ---------------- edge-parallel alpha, logits inline -----------------------------------
__global__ void alphaw_kernel(
    const int* __restrict__ esrc, const int* __restrict__ edst,
    const float* __restrict__ ssb0, const float* __restrict__ sdb0,
    const float* __restrict__ ssb1, const float* __restrict__ sdb1,
    const float* __restrict__ msl, const float* __restrict__ msd,
    float* __restrict__ al0, float* __restrict__ al1)
{
    int t = blockIdx.x * 256 + threadIdx.x;
    if (t >= NE * 16) return;
    int e = t >> 4, h = t & 15;
    int s = esrc[e], d = edst[e];
    float a0 = lrelu(ssb0[s * 16 + h] + sdb0[d * 16 + h]);
    al0[t] = __expf(a0 - msl[d * 32 + h]) / msl[d * 32 + 16 + h];
    float a1 = lrelu(ssb1[d * 16 + h] + sdb1[s * 16 + h]);
    al1[t] = __expf(a1 - msd[s * 32 + h]) / msd[s * 32 + 16 + h];
}

// ---------------- CSR build ----------------
__global__ void hist_kernel(const int* __restrict__ esrc, const int* __restrict__ edst,
                            int* __restrict__ degl, int* __restrict__ degd)
{
    int e = blockIdx.x * blockDim.x + threadIdx.x;
    if (e >= NE) return;
    atomicAdd(&degl[edst[e]], 1);
    atomicAdd(&degd[esrc[e]], 1);
}

__global__ __launch_bounds__(1024) void scan2_kernel(
    const int* __restrict__ degA, int* __restrict__ offA, int nA,
    const int* __restrict__ degB, int* __restrict__ offB, int nB)
{
    __shared__ int ps[1024];
    const int* deg = blockIdx.x ? degB : degA;
    int* off = blockIdx.x ? offB : offA;
    int n = blockIdx.x ? nB : nA;
    int tid = threadIdx.x;
    int chunk = (n + 1023) >> 10;
    int start = tid * chunk, end = min(start + chunk, n);
    int p = 0;
    for (int i = start; i < end; ++i) p += deg[i];
    ps[tid] = p;
    __syncthreads();
    for (int o = 1; o < 1024; o <<= 1) {
        int v = (tid >= o) ? ps[tid - o] : 0;
        __syncthreads();
        ps[tid] += v;
        __syncthreads();
    }
    int run = ps[tid] - p;
    for (int i = start; i < end; ++i) { off[i] = run; run += deg[i]; }
    if (tid == 1023) off[n] = ps[1023];
}

__global__ void scatter_kernel(const int* __restrict__ esrc, const int* __restrict__ edst,
                               const int* __restrict__ offl, const int* __restrict__ offd,
                               int* __restrict__ curl, int* __restrict__ curd,
                               int* __restrict__ csrl, int* __restrict__ csrd)
{
    int e = blockIdx.x * blockDim.x + threadIdx.x;
    if (e >= NE) return;
    int dl = edst[e]; int p = atomicAdd(&curl[dl], 1); csrl[offl[dl] + p] = e;
    int dd = esrc[e]; int q = atomicAdd(&curd[dd], 1); csrd[offd[dd] + q] = e;
}

// ---------------- fused per-head aggregation -> packed fragment-tiled hagg -------------
__global__ __launch_bounds__(256) void hagg_kernel(
    const float* __restrict__ hsrc,   // [n_src, 128]
    const float* __restrict__ alpha,  // [NE, 16]
    const int* __restrict__ off, const int* __restrict__ csr, const int* __restrict__ srcidx,
    unsigned int* __restrict__ haggP)
{
    __shared__ float alpha_s[2][8][17];
    __shared__ int src_s[2][8];
    const int d0 = blockIdx.x * 2;
    const int tid = threadIdx.x;

    const int half = tid >> 7;
    const int c = tid & 127;
    const int d = d0 + half;
    const int my_e0 = off[d];
    const int my_deg = off[d + 1] - my_e0;
    const int deg0 = off[d0 + 1] - off[d0];
    const int deg1 = off[d0 + 2] - off[d0 + 1];
    const int degmax = deg0 > deg1 ? deg0 : deg1;
    const int ntrip = (degmax + 7) >> 3;

    float acc[16];
#pragma unroll
    for (int h = 0; h < 16; ++h) acc[h] = 0.f;

    for (int trip = 0; trip < ntrip; ++trip) {
        int ce = trip * 8;
        {
            int ei = c >> 4, h = c & 15;
            if (ce + ei < my_deg) {
                int eid = csr[my_e0 + ce + ei];
                alpha_s[half][ei][h] = alpha[(size_t)eid * 16 + h];
                if (h == 0) src_s[half][ei] = srcidx[eid];
            }
        }
        __syncthreads();
        int nc = min(8, my_deg - ce);
        for (int ei = 0; ei < nc; ++ei) {
            float v = hsrc[(size_t)src_s[half][ei] * 128 + c];
#pragma unroll
            for (int h = 0; h < 16; ++h)
                acc[h] += alpha_s[half][ei][h] * v;
        }
        __syncthreads();
    }

    const int t = d >> 4;
    const int lane8 = ((d & 15) + 16 * ((c >> 3) & 3)) * 8 + (c & 7);
    const int kc = c >> 5;
#pragma unroll
    for (int h = 0; h < 16; ++h) {
        float v = acc[h];
        unsigned short hb = f2bf(v);
        unsigned short lb = f2bf(v - bf2f(hb));
        size_t idx = (((size_t)t * 16 + h) * 4 + kc) * 512 + lane8;
        haggP[idx] = (unsigned int)hb | ((unsigned int)lb << 16);
    }
}

// ---------------- layer 3 merged: gather + bias + relu + mean + penalty ----------------
__global__ __launch_bounds__(256) void agg32both_kernel(
    const float* __restrict__ zs3d, const float* __restrict__ zs3l,
    const float* __restrict__ alpha0, const float* __restrict__ alpha1,
    const int* __restrict__ offl, const int* __restrict__ csrl,
    const int* __restrict__ offd, const int* __restrict__ csrd,
    const int* __restrict__ esrc, const int* __restrict__ edst,
    const float* __restrict__ bias512,
    const float* __restrict__ pw, const float* __restrict__ pb,
    float* __restrict__ hlp, float* __restrict__ hdp)
{
    __shared__ float alpha_s[16][17];
    __shared__ int src_s[16];
    __shared__ float lds_out[512];
    __shared__ float hrow[32];
    int d = blockIdx.x;
    const float* zs; const float* alpha;
    const int* off; const int* csr; const int* srcidx;
    const float* bias; const float* pwt; const float* pbt; float* out;
    if (d < NL) {
        zs = zs3d; alpha = alpha0; off = offl; csr = csrl; srcidx = esrc;
        bias = bias512; pwt = pw + 32; pbt = pb + 1; out = hlp;
    } else {
        d -= NL;
        zs = zs3l; alpha = alpha1; off = offd; csr = csrd; srcidx = edst;
        bias = bias512 + 512; pwt = pw; pbt = pb; out = hdp;
    }
    const int tid = threadIdx.x;
    const int e0 = off[d], e1 = off[d + 1];

    float acc0 = 0.f, acc1 = 0.f;
    const int hsel = tid >> 4;

    for (int ce = e0; ce < e1; ce += 16) {
        int nc = min(16, e1 - ce);
        if (tid < nc * 16) {
            int ei = tid >> 4, h = tid & 15;
            int eid = csr[ce + ei];
            alpha_s[ei][h] = alpha[(size_t)eid * 16 + h];
            if (h == 0) src_s[ei] = srcidx[eid];
        }
        __syncthreads();
        for (int ei = 0; ei < nc; ++ei) {
            float a = alpha_s[ei][hsel];
            float2 v = *(const float2*)(zs + (size_t)src_s[ei] * 512 + tid * 2);
            acc0 += a * v.x;
            acc1 += a * v.y;
        }
        __syncthreads();
    }

    lds_out[tid * 2] = fmaxf(acc0 + bias[tid * 2], 0.f);
    lds_out[tid * 2 + 1] = fmaxf(acc1 + bias[tid * 2 + 1], 0.f);
    __syncthreads();
    if (tid < 32) {
        float s = 0.f;
#pragma unroll
        for (int hh = 0; hh < 16; ++hh) s += lds_out[hh * 32 + tid];
        hrow[tid] = s * (1.f / 16.f);
    }
    __syncthreads();
    if (tid < 32) {
        float t = pbt[0];
#pragma unroll
        for (int c = 0; c < 32; ++c) t += hrow[c] * pwt[c];
        out[(size_t)d * 32 + tid] = hrow[tid] * expf(t);
    }
}

// ---------------- final MLP on label edges ----------------
__global__ __launch_bounds__(256) void mlp_kernel(
    const float* __restrict__ hd, const float* __restrict__ hl,
    const int* __restrict__ ls, const int* __restrict__ ld,
    const float* __restrict__ w1, const float* __restrict__ b1,
    const float* __restrict__ w2, const float* __restrict__ b2,
    float* __restrict__ out, int M)
{
    __shared__ float w1s[64 * 64];
    __shared__ float b1s[64];
    __shared__ float w2s[64];
    int tid = threadIdx.x;
#pragma unroll
    for (int i = 0; i < 16; ++i) w1s[tid + i * 256] = w1[tid + i * 256];
    if (tid < 64) { b1s[tid] = b1[tid]; w2s[tid] = w2[tid]; }
    __syncthreads();
    int m = blockIdx.x * 256 + tid;
    if (m >= M) return;
    float f[64];
    const float* hp = hd + (size_t)ls[m] * 32;
    const float* lp = hl + (size_t)ld[m] * 32;
#pragma unroll
    for (int c = 0; c < 32; ++c) { f[c] = hp[c]; f[32 + c] = lp[c]; }
    float o = b2[0];
    for (int j = 0; j < 64; ++j) {
        float hj = b1s[j];
#pragma unroll
        for (int k = 0; k < 64; ++k) hj += f[k] * w1s[k * 64 + j];
        hj = fmaxf(hj, 0.f);
        o += hj * w2s[j];
    }
    out[m] = o;
}

extern "C" void kernel_launch(void* const* d_in, const int* in_sizes, int n_in,
                              void* d_out, int out_size, void* d_ws, size_t ws_size,
                              hipStream_t stream)
{
    const float* x_d = (const float*)d_in[0];
    const float* x_l = (const float*)d_in[1];
    const int* node_id_d = (const int*)d_in[2];
    const int* node_id_l = (const int*)d_in[3];
    const int* edge_src = (const int*)d_in[4];
    const int* edge_dst = (const int*)d_in[5];
    const int* label_src = (const int*)d_in[6];
    const int* label_dst = (const int*)d_in[7];
    const float* emb_d = (const float*)d_in[8];
    const float* emb_l = (const float*)d_in[9];
    const float* lin_dw = (const float*)d_in[10];
    const float* lin_db = (const float*)d_in[11];
    const float* lin_lw = (const float*)d_in[12];
    const float* lin_lb = (const float*)d_in[13];
    const float* Ws[3] = {(const float*)d_in[14], (const float*)d_in[19], (const float*)d_in[24]};
    const float* Wd[3] = {(const float*)d_in[15], (const float*)d_in[20], (const float*)d_in[25]};
    const float* as_[3] = {(const float*)d_in[16], (const float*)d_in[21], (const float*)d_in[26]};
    const float* ad_[3] = {(const float*)d_in[17], (const float*)d_in[22], (const float*)d_in[27]};
    const float* bb[3] = {(const float*)d_in[18], (const float*)d_in[23], (const float*)d_in[28]};
    const float* pw = (const float*)d_in[29];
    const float* pb = (const float*)d_in[30];
    const float* fc1w = (const float*)d_in[31];
    const float* fc1b = (const float*)d_in[32];
    const float* fc2w = (const float*)d_in[33];
    const float* fc2b = (const float*)d_in[34];

    char* wsb = (char*)d_ws;
    size_t woff = 0;
    auto carve = [&](size_t bytes) -> void* {
        woff = (woff + 255) & ~(size_t)255;
        void* p = wsb + woff;
        woff += bytes;
        return p;
    };
    float* hdA = (float*)carve((size_t)ND * 128 * 4);
    float* hlA = (float*)carve((size_t)NL * 128 * 4);
    float* hdB = (float*)carve((size_t)ND * 128 * 4);
    float* hlB = (float*)carve((size_t)NL * 128 * 4);
    unsigned int* haggP = (unsigned int*)carve((size_t)NL * 2048 * 4);  // L3 reuses as zs3d/zs3l
    unsigned short* WtH = (unsigned short*)carve((size_t)2 * 2 * 2048 * 128 * 2);
    unsigned short* WtL = (unsigned short*)carve((size_t)2 * 2 * 2048 * 128 * 2);
    float* ssb0 = (float*)carve((size_t)ND * 16 * 4);
    float* sdb0 = (float*)carve((size_t)NL * 16 * 4);
    float* ssb1 = (float*)carve((size_t)NL * 16 * 4);
    float* sdb1 = (float*)carve((size_t)ND * 16 * 4);
    float* al0 = (float*)carve((size_t)NE * 16 * 4);
    float* al1 = (float*)carve((size_t)NE * 16 * 4);
    float* msl = (float*)carve((size_t)NL * 32 * 4);
    float* msd = (float*)carve((size_t)ND * 32 * 4);
    float* fw3 = (float*)carve((size_t)3 * 4 * 2048 * 4);
    int* degl = (int*)carve((size_t)(2 * (NL + ND)) * 4);
    int* degd = degl + NL;
    int* curl = degd + ND;
    int* curd = curl + NL;
    int* offl = (int*)carve((size_t)(NL + 1) * 4);
    int* offd = (int*)carve((size_t)(ND + 1) * 4);
    int* csrl = (int*)carve((size_t)NE * 4);
    int* csrd = (int*)carve((size_t)NE * 4);
    float* hdp = (float*)carve((size_t)ND * 32 * 4);
    float* hlp = (float*)carve((size_t)NL * 32 * 4);

    hipMemsetAsync(degl, 0, (size_t)2 * (NL + ND) * 4, stream);

    hist_kernel<<<(NE + 255) / 256, 256, 0, stream>>>(edge_src, edge_dst, degl, degd);
    scan2_kernel<<<2, 1024, 0, stream>>>(degl, offl, NL, degd, offd, ND);
    scatter_kernel<<<(NE + 255) / 256, 256, 0, stream>>>(edge_src, edge_dst, offl, offd, curl, curd, csrl, csrd);

    fold3_kernel<<<(3 * 8192 + 255) / 256, 256, 0, stream>>>(
        Ws[0], Wd[0], as_[0], ad_[0], Ws[1], Wd[1], as_[1], ad_[1],
        Ws[2], Wd[2], as_[2], ad_[2], fw3);
    wt2_kernel<<<(2 * 524288 + 255) / 256, 256, 0, stream>>>(Ws[0], Ws[1], WtH, WtL);

    inlin_kernel<<<dim3(2, 750), 256, 0, stream>>>(
        x_d, x_l, lin_dw, lin_lw, lin_db, lin_lb, emb_d, emb_l,
        node_id_d, node_id_l, hdA, hlA);

    float* hd_cur = hdA; float* hd_nxt = hdB;
    float* hl_cur = hlA; float* hl_nxt = hlB;

    const int grid_e16 = (NE * 16 + 255) / 256;
    const int grid_ms = ((NL + ND) * 16 + 255) / 256;
    // XCD-swizzled 8-way gemm2r grids: 64 blocks per group of 8 m-tiles
    const int gridNL = ((NL / 64 + 7) / 8) * 64;   // 250 tiles -> 2048 blocks
    const int gridND = ((ND / 64 + 7) / 8) * 64;   // 125 tiles -> 1024 blocks

    // ---- layers 1-2: aggregate-then-project (split-bf16 MFMA, fused head-mean) ----
    for (int L = 0; L < 2; ++L) {
        const float* fw = fw3 + (size_t)L * 8192;
        const unsigned short* wtH = WtH + (size_t)L * 524288;
        const unsigned short* wtL = WtL + (size_t)L * 524288;

        score2both_kernel<<<ND / 16 + NL / 16, 256, 0, stream>>>(
            hd_cur, hl_cur, fw, ssb0, sdb1, sdb0, ssb1);
        ms_kernel<<<grid_ms, 256, 0, stream>>>(edge_src, edge_dst, ssb0, sdb0, ssb1, sdb1,
                                               offl, csrl, msl, offd, csrd, msd);
        alphaw_kernel<<<grid_e16, 256, 0, stream>>>(edge_src, edge_dst, ssb0, sdb0, ssb1, sdb1,
                                                    msl, msd, al0, al1);

        // edge type 0: disease -> lncrna (dst = lncrna)
        hagg_kernel<<<NL / 2, 256, 0, stream>>>(hd_cur, al0, offl, csrl, edge_src, haggP);
        gemm2r_kernel<<<gridNL, 256, 0, stream>>>(haggP, wtH, wtL, bb[L], hl_nxt, NL);

        // edge type 1: lncrna -> disease (dst = disease)
        hagg_kernel<<<ND / 2, 256, 0, stream>>>(hl_cur, al1, offd, csrd, edge_dst, haggP);
        gemm2r_kernel<<<gridND, 256, 0, stream>>>(haggP,
                                                  wtH + (size_t)2048 * 128, wtL + (size_t)2048 * 128,
                                                  bb[L] + 2048, hd_nxt, ND);

        float* t;
        t = hd_cur; hd_cur = hd_nxt; hd_nxt = t;
        t = hl_cur; hl_cur = hl_nxt; hl_nxt = t;
    }

    // ---- layer 3: project-then-aggregate (fp32), merged dispatches ----
    {
        const float* fw = fw3 + 2 * 8192;
        float* zs3d = (float*)haggP;
        float* zs3l = (float*)haggP + (size_t)ND * 512;
        score2both_kernel<<<ND / 16 + NL / 16, 256, 0, stream>>>(
            hd_cur, hl_cur, fw, ssb0, sdb1, sdb0, ssb1);
        ms_kernel<<<grid_ms, 256, 0, stream>>>(edge_src, edge_dst, ssb0, sdb0, ssb1, sdb1,
                                               offl, csrl, msl, offd, csrd, msd);
        alphaw_kernel<<<grid_e16, 256, 0, stream>>>(edge_src, edge_dst, ssb0, sdb0, ssb1, sdb1,
                                                    msl, msd, al0, al1);

        gemm3_kernel<<<dim3(512 / BN, 125 + 250), 256, 0, stream>>>(
            hd_cur, hl_cur, Ws[2], zs3d, zs3l);

        agg32both_kernel<<<NL + ND, 256, 0, stream>>>(
            zs3d, zs3l, al0, al1,
            offl, csrl, offd, csrd, edge_src, edge_dst,
            bb[2], pw, pb, hlp, hdp);
    }

    mlp_kernel<<<(NM + 255) / 256, 256, 0, stream>>>(hdp, hlp, label_src, label_dst,
                                                     fc1w, fc1b, fc2w, fc2b, (float*)d_out, NM);
}

// Round 19
// 760.747 us; speedup vs baseline: 1.0564x; 1.0564x over previous
//
#include <hip/hip_runtime.h>
#include <cstdint>
#include <cstddef>

#define ND 8000
#define NL 16000
#define NE 60000
#define NM 50000

#define BM 64
#define BN 64
#define BK 16

typedef __attribute__((ext_vector_type(8))) short bf16x8;
typedef __attribute__((ext_vector_type(4))) float f32x4;
typedef __attribute__((ext_vector_type(8))) unsigned int u32x8;

__device__ __forceinline__ unsigned short f2bf(float x) {
    unsigned int u = __float_as_uint(x);
    unsigned int r = (u + 0x7FFFu + ((u >> 16) & 1u)) >> 16;
    return (unsigned short)r;
}
__device__ __forceinline__ float bf2f(unsigned short b) {
    return __uint_as_float(((unsigned int)b) << 16);
}
__device__ __forceinline__ float lrelu(float x) {
    return x >= 0.f ? x : 0.2f * x;
}

// ---------------- merged layer-3 GEMM: zs3d = hd @ W[0], zs3l = hl @ W[1] --------------
__global__ __launch_bounds__(256) void gemm3_kernel(
    const float* __restrict__ hd, const float* __restrict__ hl,
    const float* __restrict__ W,   // [2,128,512]
    float* __restrict__ zs3d, float* __restrict__ zs3l)
{
    __shared__ float As[BK][BM + 4];
    __shared__ float Bs[BK][BN + 4];
    int mt = blockIdx.y;
    const float* A; const float* B; float* Cm;
    if (mt < 125) { A = hd; B = W; Cm = zs3d; }
    else { mt -= 125; A = hl; B = W + 128 * 512; Cm = zs3l; }
    const int tid = threadIdx.x;
    const int tx = tid & 15, ty = tid >> 4;
    const int bm = mt * BM, bn = blockIdx.x * BN;
    float acc[4][4] = {};
    for (int k0 = 0; k0 < 128; k0 += BK) {
#pragma unroll
        for (int i = 0; i < 4; ++i) {
            int idx = tid + i * 256;
            int ml = idx >> 4, kl = idx & 15;
            As[kl][ml] = A[(size_t)(bm + ml) * 128 + k0 + kl];
        }
#pragma unroll
        for (int i = 0; i < 4; ++i) {
            int idx = tid + i * 256;
            int kl = idx >> 6, nl = idx & 63;
            Bs[kl][nl] = B[(size_t)(k0 + kl) * 512 + bn + nl];
        }
        __syncthreads();
#pragma unroll
        for (int k = 0; k < BK; ++k) {
            float4 av = *(const float4*)&As[k][ty * 4];
            float4 bv = *(const float4*)&Bs[k][tx * 4];
            float a4[4] = {av.x, av.y, av.z, av.w};
            float b4[4] = {bv.x, bv.y, bv.z, bv.w};
#pragma unroll
            for (int i = 0; i < 4; ++i)
#pragma unroll
                for (int j = 0; j < 4; ++j)
                    acc[i][j] += a4[i] * b4[j];
        }
        __syncthreads();
    }
#pragma unroll
    for (int i = 0; i < 4; ++i) {
        int gm = bm + ty * 4 + i;
        int gn0 = bn + tx * 4;
        float4 v;
        float* vp = &v.x;
#pragma unroll
        for (int j = 0; j < 4; ++j) vp[j] = acc[i][j];
        *(float4*)&Cm[(size_t)gm * 512 + gn0] = v;
    }
}

// ---------------- fused input linears, 32-row tiles, register double-buffer ------------
__global__ __launch_bounds__(256) void inlin_kernel(
    const float* __restrict__ x_d, const float* __restrict__ x_l,
    const float* __restrict__ wd, const float* __restrict__ wl,
    const float* __restrict__ bd, const float* __restrict__ bl,
    const float* __restrict__ embd, const float* __restrict__ embl,
    const int* __restrict__ nidd, const int* __restrict__ nidl,
    float* __restrict__ hd, float* __restrict__ hl)
{
    __shared__ float As[BK][32 + 4];
    __shared__ float Bs[BK][BN + 4];
    int mt = blockIdx.y;
    const float* A; const float* B; const float* bias; const float* emb;
    const int* nid; float* out;
    int K;
    if (mt < 250) {
        A = x_d; B = wd; bias = bd; emb = embd; nid = nidd; out = hd; K = 412;
    } else {
        mt -= 250;
        A = x_l; B = wl; bias = bl; emb = embl; nid = nidl; out = hl; K = 240;
    }
    const int tid = threadIdx.x;
    const int tx = tid & 15, ty = tid >> 4;
    const int bm = mt * 32, bn = blockIdx.x * BN;

    const int aml0 = tid >> 4, akl0 = tid & 15;
    const int aml1 = (tid + 256) >> 4, akl1 = tid & 15;
    const int bkl = tid >> 6, bnl = tid & 63;

    float pa[2], pb[4];
    {
        int gk0 = akl0, gk1 = akl1;
        pa[0] = (gk0 < K) ? A[(size_t)(bm + aml0) * K + gk0] : 0.f;
        pa[1] = (gk1 < K) ? A[(size_t)(bm + aml1) * K + gk1] : 0.f;
#pragma unroll
        for (int i = 0; i < 4; ++i) {
            int gk = bkl + i * 4;
            pb[i] = (gk < K) ? B[(size_t)gk * 128 + bn + bnl] : 0.f;
        }
    }

    float acc[2][4] = {};
    for (int k0 = 0; k0 < K; k0 += BK) {
        As[akl0][aml0] = pa[0];
        As[akl1][aml1] = pa[1];
#pragma unroll
        for (int i = 0; i < 4; ++i)
            Bs[bkl + i * 4][bnl] = pb[i];
        __syncthreads();
        int kn = k0 + BK;
        if (kn < K) {
            int gk0 = kn + akl0, gk1 = kn + akl1;
            pa[0] = (gk0 < K) ? A[(size_t)(bm + aml0) * K + gk0] : 0.f;
            pa[1] = (gk1 < K) ? A[(size_t)(bm + aml1) * K + gk1] : 0.f;
#pragma unroll
            for (int i = 0; i < 4; ++i) {
                int gk = kn + bkl + i * 4;
                pb[i] = (gk < K) ? B[(size_t)gk * 128 + bn + bnl] : 0.f;
            }
        }
#pragma unroll
        for (int k = 0; k < BK; ++k) {
            float a0 = As[k][ty * 2];
            float a1 = As[k][ty * 2 + 1];
            float4 bv = *(const float4*)&Bs[k][tx * 4];
            float b4[4] = {bv.x, bv.y, bv.z, bv.w};
#pragma unroll
            for (int j = 0; j < 4; ++j) {
                acc[0][j] += a0 * b4[j];
                acc[1][j] += a1 * b4[j];
            }
        }
        __syncthreads();
    }
#pragma unroll
    for (int i = 0; i < 2; ++i) {
        int gm = bm + ty * 2 + i;
        int gn0 = bn + tx * 4;
        const float* ep = emb + (size_t)nid[gm] * 128 + gn0;
        float4 v;
        float* vp = &v.x;
#pragma unroll
        for (int j = 0; j < 4; ++j)
            vp[j] = acc[i][j] + bias[gn0 + j] + ep[j];
        *(float4*)&out[(size_t)gm * 128 + gn0] = v;
    }
}

// ---------------- W transpose + split-bf16 into MFMA-fragment tiling, BOTH layers ------
__global__ void wt2_kernel(const float* __restrict__ W0, const float* __restrict__ W1,
                           unsigned short* __restrict__ WtH, unsigned short* __restrict__ WtL)
{
    int gid = blockIdx.x * 256 + threadIdx.x;
    if (gid >= 2 * 2 * 128 * 2048) return;
    int l = gid >> 19;
    int rem0 = gid & 524287;
    int dir = rem0 >> 18;
    int rem = rem0 & 262143;
    int k = rem >> 11, n = rem & 2047;
    const float* W = l ? W1 : W0;
    float v = W[(size_t)dir * 262144 + (size_t)k * 2048 + n];
    unsigned short hb = f2bf(v);
    unsigned short lb = f2bf(v - bf2f(hb));
    int u = n >> 4;
    int lane = (n & 15) + 16 * ((k >> 3) & 3);
    size_t o = (size_t)l * 524288 + (size_t)dir * 262144 +
               ((size_t)u * 4 + (k >> 5)) * 512 + lane * 8 + (k & 7);
    WtH[o] = hb;
    WtL[o] = lb;
}

// ---------------- fused per-head projection + bias + relu + HEAD-MEAN (layers 1-2) ----
// 4-way column split, XCD-aware: i -> cb=(i>>3)&3, mt=(i>>5)*8+(i&7); the 4 blocks
// sharing m-tile mt have equal i%8 -> same XCD -> A slice from that XCD's L2.
__global__ __launch_bounds__(256) void gemm2r_kernel(
    const unsigned int* __restrict__ haggP,
    const unsigned short* __restrict__ WtH, const unsigned short* __restrict__ WtL,
    const float* __restrict__ bias, float* __restrict__ out, int M)
{
    const int wave = threadIdx.x >> 6;
    const int lane = threadIdx.x & 63;
    const int i = blockIdx.x;
    const int cb = (i >> 3) & 3;             // column quarter
    const int mt = (i >> 5) * 8 + (i & 7);   // m-tile
    if (mt >= (M >> 6)) return;
    const int m0 = mt * 64 + wave * 16;
    const int t = m0 >> 4;
    const int row = lane & 15;
    const int quad = lane >> 4;

    f32x4 mean[2] = {};

    for (int h = 0; h < 16; ++h) {
        f32x4 accH[2], accL[2];
#pragma unroll
        for (int ctl = 0; ctl < 2; ++ctl) {
            float bv = bias[h * 128 + cb * 32 + ctl * 16 + row];
            accH[ctl] = (f32x4){bv, bv, bv, bv};
            accL[ctl] = (f32x4){0.f, 0.f, 0.f, 0.f};
        }
#pragma unroll
        for (int kc = 0; kc < 4; ++kc) {
            const size_t aoff = (((size_t)t * 16 + h) * 4 + kc) * 512 + lane * 8;
            u32x8 p = *(const u32x8*)(haggP + aoff);
            bf16x8 aH, aL;
#pragma unroll
            for (int ii = 0; ii < 8; ++ii) {
                aH[ii] = (short)(p[ii] & 0xffffu);
                aL[ii] = (short)(p[ii] >> 16);
            }
#pragma unroll
            for (int ctl = 0; ctl < 2; ++ctl) {
                const int u = h * 8 + cb * 2 + ctl;
                const size_t boff = ((size_t)u * 4 + kc) * 512 + lane * 8;
                bf16x8 bH = *(const bf16x8*)(WtH + boff);
                bf16x8 bL = *(const bf16x8*)(WtL + boff);
                accH[ctl] = __builtin_amdgcn_mfma_f32_16x16x32_bf16(aH, bH, accH[ctl], 0, 0, 0);
                accL[ctl] = __builtin_amdgcn_mfma_f32_16x16x32_bf16(aH, bL, accL[ctl], 0, 0, 0);
                accL[ctl] = __builtin_amdgcn_mfma_f32_16x16x32_bf16(aL, bH, accL[ctl], 0, 0, 0);
            }
        }
#pragma unroll
        for (int ctl = 0; ctl < 2; ++ctl)
#pragma unroll
            for (int r = 0; r < 4; ++r)
                mean[ctl][r] += fmaxf(accH[ctl][r] + accL[ctl][r], 0.f);
    }

#pragma unroll
    for (int ctl = 0; ctl < 2; ++ctl) {
        int c = cb * 32 + ctl * 16 + row;
#pragma unroll
        for (int r = 0; r < 4; ++r) {
            int gm = m0 + quad * 4 + r;
            out[(size_t)gm * 128 + c] = mean[ctl][r] * (1.f / 16.f);
        }
    }
}

// ---------------- fold for ALL 3 layers ------------------------------------------------
__global__ void fold3_kernel(
    const float* __restrict__ Ws1, const float* __restrict__ Wd1,
    const float* __restrict__ as1, const float* __restrict__ ad1,
    const float* __restrict__ Ws2, const float* __restrict__ Wd2,
    const float* __restrict__ as2, const float* __restrict__ ad2,
    const float* __restrict__ Ws3, const float* __restrict__ Wd3,
    const float* __restrict__ as3, const float* __restrict__ ad3,
    float* __restrict__ fw3)
{
    int gid = blockIdx.x * blockDim.x + threadIdx.x;
    if (gid >= 3 * 4 * 128 * 16) return;
    int l = gid / 8192, rem1 = gid % 8192;
    int f = rem1 / 2048, rem = rem1 % 2048;
    int k = rem >> 4, h = rem & 15;
    int Ntot = (l == 2) ? 512 : 2048;
    int C = Ntot >> 4;
    const float* W;
    const float* a;
    if (l == 0) { W = (f & 1) ? Wd1 : Ws1; a = (f & 1) ? ad1 : as1; }
    else if (l == 1) { W = (f & 1) ? Wd2 : Ws2; a = (f & 1) ? ad2 : as2; }
    else { W = (f & 1) ? Wd3 : Ws3; a = (f & 1) ? ad3 : as3; }
    if (f >= 2) { W += 128 * Ntot; a += 16 * C; }
    float s = 0.f;
    for (int c = 0; c < C; ++c) s += W[(size_t)k * Ntot + h * C + c] * a[h * C + c];
    fw3[gid] = s;
}

// ---------------- score2both: all four folded scores of a layer ------------------------
__global__ __launch_bounds__(256) void score2both_kernel(
    const float* __restrict__ Hd, const float* __restrict__ Hl,
    const float* __restrict__ fw,
    float* __restrict__ ssb0, float* __restrict__ sdb1,
    float* __restrict__ sdb0, float* __restrict__ ssb1)
{
    __shared__ float hs[16 * 128];
    __shared__ float wa[128 * 16];
    __shared__ float wb[128 * 16];
    int b = blockIdx.x;
    const float* Hf; const float* WfA; const float* WfB;
    float* outA; float* outB; int n0;
    if (b < ND / 16) {
        Hf = Hd; WfA = fw; WfB = fw + 3 * 2048; outA = ssb0; outB = sdb1; n0 = b * 16;
    } else {
        Hf = Hl; WfA = fw + 1 * 2048; WfB = fw + 2 * 2048; outA = sdb0; outB = ssb1;
        n0 = (b - ND / 16) * 16;
    }
    int tid = threadIdx.x;
#pragma unroll
    for (int i = 0; i < 8; ++i) {
        int idx = tid + i * 256;
        int nl = idx >> 7, k = idx & 127;
        hs[idx] = Hf[(size_t)(n0 + nl) * 128 + k];
        wa[idx] = WfA[idx];
        wb[idx] = WfB[idx];
    }
    __syncthreads();
    int nl = tid >> 4, h = tid & 15;
    float sa = 0.f, sb = 0.f;
    for (int k = 0; k < 128; ++k) {
        float hv = hs[nl * 128 + k];
        sa += hv * wa[k * 16 + h];
        sb += hv * wb[k * 16 + h];
    }
    int gn = n0 + nl;
    outA[gn * 16 + h] = sa;
    outB[gn * 16 + h] = sb;
}

// ---------------- per-(dst,head) online softmax max/sum, logits inline -----------------
__global__ void ms_kernel(
    const int* __restrict__ esrc, const int* __restrict__ edst,
    const float* __restrict__ ssb0, const float* __restrict__ sdb0,
    const float* __restrict__ ssb1, const float* __restrict__ sdb1,
    const int* __restrict__ offl, const int* __restrict__ csrl, float* __restrict__ msl,
    const int* __restrict__ offd, const int* __restrict__ csrd, float* __restrict__ msd)
{
    int t = blockIdx.x * 256 + threadIdx.x;
    const int* off; const int* csr; const int* srcidx;
    const float* ss; float sdv; float* ms; int d, h;
    if (t < NL * 16) {
        d = t >> 4; h = t & 15;
        off = offl; csr = csrl; srcidx = esrc; ss = ssb0;
        sdv = sdb0[d * 16 + h]; ms = msl;
    } else {
        t -= NL * 16;
        if (t >= ND * 16) return;
        d = t >> 4; h = t & 15;
        off = offd; csr = csrd; srcidx = edst; ss = ssb1;
        sdv = sdb1[d * 16 + h]; ms = msd;
    }
    int e0 = off[d], e1 = off[d + 1];
    float m = -1e30f, s = 0.f;
    for (int e = e0; e < e1; ++e) {
        int sn = srcidx[csr[e]];
        float a = lrelu(ss[sn * 16 + h] + sdv);
        if (a > m) { s = s * __expf(m - a) + 1.f; m = a; }
        else s += __expf(a - m);
    }
    ms[d * 32 + h] = m;
    ms[d * 32 + 16 + h] = s + 1e-16f;
}

// ---------------- CSR build ----------------
__global__ void hist_kernel(const int* __restrict__ esrc, const int* __restrict__ edst,
                            int* __restrict__ degl, int* __restrict__ degd)
{
    int e = blockIdx.x * blockDim.x + threadIdx.x;
    if (e >= NE) return;
    atomicAdd(&degl[edst[e]], 1);
    atomicAdd(&degd[esrc[e]], 1);
}

__global__ __launch_bounds__(1024) void scan2_kernel(
    const int* __restrict__ degA, int* __restrict__ offA, int nA,
    const int* __restrict__ degB, int* __restrict__ offB, int nB)
{
    __shared__ int ps[1024];
    const int* deg = blockIdx.x ? degB : degA;
    int* off = blockIdx.x ? offB : offA;
    int n = blockIdx.x ? nB : nA;
    int tid = threadIdx.x;
    int chunk = (n + 1023) >> 10;
    int start = tid * chunk, end = min(start + chunk, n);
    int p = 0;
    for (int i = start; i < end; ++i) p += deg[i];
    ps[tid] = p;
    __syncthreads();
    for (int o = 1; o < 1024; o <<= 1) {
        int v = (tid >= o) ? ps[tid - o] : 0;
        __syncthreads();
        ps[tid] += v;
        __syncthreads();
    }
    int run = ps[tid] - p;
    for (int i = start; i < end; ++i) { off[i] = run; run += deg[i]; }
    if (tid == 1023) off[n] = ps[1023];
}

__global__ void scatter_kernel(const int* __restrict__ esrc, const int* __restrict__ edst,
                               const int* __restrict__ offl, const int* __restrict__ offd,
                               int* __restrict__ curl, int* __restrict__ curd,
                               int* __restrict__ csrl, int* __restrict__ csrd)
{
    int e = blockIdx.x * blockDim.x + threadIdx.x;
    if (e >= NE) return;
    int dl = edst[e]; int p = atomicAdd(&curl[dl], 1); csrl[offl[dl] + p] = e;
    int dd = esrc[e]; int q = atomicAdd(&curd[dd], 1); csrd[offd[dd] + q] = e;
}

// ---------------- fused alpha + per-head aggregation -> packed fragment-tiled hagg -----
// alpha computed inline from scores + precomputed ms; two consecutive dst nodes/block.
__global__ __launch_bounds__(256) void hagg_kernel(
    const float* __restrict__ hsrc,   // [n_src, 128]
    const float* __restrict__ ss,     // src scores [n_src, 16]
    const float* __restrict__ sd,     // dst scores [n_dst, 16]
    const float* __restrict__ ms,     // [n_dst, 32] (m | s)
    const int* __restrict__ off, const int* __restrict__ csr, const int* __restrict__ srcidx,
    unsigned int* __restrict__ haggP)
{
    __shared__ float alpha_s[2][8][17];
    __shared__ int src_s[2][8];
    const int d0 = blockIdx.x * 2;
    const int tid = threadIdx.x;

    const int half = tid >> 7;
    const int c = tid & 127;
    const int d = d0 + half;
    const int my_e0 = off[d];
    const int my_deg = off[d + 1] - my_e0;
    const int deg0 = off[d0 + 1] - off[d0];
    const int deg1 = off[d0 + 2] - off[d0 + 1];
    const int degmax = deg0 > deg1 ? deg0 : deg1;
    const int ntrip = (degmax + 7) >> 3;

    float acc[16];
#pragma unroll
    for (int h = 0; h < 16; ++h) acc[h] = 0.f;

    for (int trip = 0; trip < ntrip; ++trip) {
        int ce = trip * 8;
        {
            int ei = c >> 4, h = c & 15;
            if (ce + ei < my_deg) {
                int eid = csr[my_e0 + ce + ei];
                int sn = srcidx[eid];
                float a = lrelu(ss[sn * 16 + h] + sd[d * 16 + h]);
                alpha_s[half][ei][h] = __expf(a - ms[d * 32 + h]) / ms[d * 32 + 16 + h];
                if (h == 0) src_s[half][ei] = sn;
            }
        }
        __syncthreads();
        int nc = min(8, my_deg - ce);
        for (int ei = 0; ei < nc; ++ei) {
            float v = hsrc[(size_t)src_s[half][ei] * 128 + c];
#pragma unroll
            for (int h = 0; h < 16; ++h)
                acc[h] += alpha_s[half][ei][h] * v;
        }
        __syncthreads();
    }

    const int t = d >> 4;
    const int lane8 = ((d & 15) + 16 * ((c >> 3) & 3)) * 8 + (c & 7);
    const int kc = c >> 5;
#pragma unroll
    for (int h = 0; h < 16; ++h) {
        float v = acc[h];
        unsigned short hb = f2bf(v);
        unsigned short lb = f2bf(v - bf2f(hb));
        size_t idx = (((size_t)t * 16 + h) * 4 + kc) * 512 + lane8;
        haggP[idx] = (unsigned int)hb | ((unsigned int)lb << 16);
    }
}

// ---------------- layer 3 merged: alpha inline + gather + bias + relu + mean + penalty -
__global__ __launch_bounds__(256) void agg32both_kernel(
    const float* __restrict__ zs3d, const float* __restrict__ zs3l,
    const float* __restrict__ ssb0, const float* __restrict__ sdb0, const float* __restrict__ msl,
    const float* __restrict__ ssb1, const float* __restrict__ sdb1, const float* __restrict__ msd,
    const int* __restrict__ offl, const int* __restrict__ csrl,
    const int* __restrict__ offd, const int* __restrict__ csrd,
    const int* __restrict__ esrc, const int* __restrict__ edst,
    const float* __restrict__ bias512,
    const float* __restrict__ pw, const float* __restrict__ pb,
    float* __restrict__ hlp, float* __restrict__ hdp)
{
    __shared__ float alpha_s[16][17];
    __shared__ int src_s[16];
    __shared__ float lds_out[512];
    __shared__ float hrow[32];
    int d = blockIdx.x;
    const float* zs; const float* ss; const float* sd; const float* ms;
    const int* off; const int* csr; const int* srcidx;
    const float* bias; const float* pwt; const float* pbt; float* out;
    if (d < NL) {
        zs = zs3d; ss = ssb0; sd = sdb0; ms = msl;
        off = offl; csr = csrl; srcidx = esrc;
        bias = bias512; pwt = pw + 32; pbt = pb + 1; out = hlp;
    } else {
        d -= NL;
        zs = zs3l; ss = ssb1; sd = sdb1; ms = msd;
        off = offd; csr = csrd; srcidx = edst;
        bias = bias512 + 512; pwt = pw; pbt = pb; out = hdp;
    }
    const int tid = threadIdx.x;
    const int e0 = off[d], e1 = off[d + 1];

    float acc0 = 0.f, acc1 = 0.f;
    const int hsel = tid >> 4;

    for (int ce = e0; ce < e1; ce += 16) {
        int nc = min(16, e1 - ce);
        if (tid < nc * 16) {
            int ei = tid >> 4, h = tid & 15;
            int eid = csr[ce + ei];
            int sn = srcidx[eid];
            float a = lrelu(ss[sn * 16 + h] + sd[d * 16 + h]);
            alpha_s[ei][h] = __expf(a - ms[d * 32 + h]) / ms[d * 32 + 16 + h];
            if (h == 0) src_s[ei] = sn;
        }
        __syncthreads();
        for (int ei = 0; ei < nc; ++ei) {
            float a = alpha_s[ei][hsel];
            float2 v = *(const float2*)(zs + (size_t)src_s[ei] * 512 + tid * 2);
            acc0 += a * v.x;
            acc1 += a * v.y;
        }
        __syncthreads();
    }

    lds_out[tid * 2] = fmaxf(acc0 + bias[tid * 2], 0.f);
    lds_out[tid * 2 + 1] = fmaxf(acc1 + bias[tid * 2 + 1], 0.f);
    __syncthreads();
    if (tid < 32) {
        float s = 0.f;
#pragma unroll
        for (int hh = 0; hh < 16; ++hh) s += lds_out[hh * 32 + tid];
        hrow[tid] = s * (1.f / 16.f);
    }
    __syncthreads();
    if (tid < 32) {
        float t = pbt[0];
#pragma unroll
        for (int c = 0; c < 32; ++c) t += hrow[c] * pwt[c];
        out[(size_t)d * 32 + tid] = hrow[tid] * expf(t);
    }
}

// ---------------- final MLP on label edges ----------------
__global__ __launch_bounds__(256) void mlp_kernel(
    const float* __restrict__ hd, const float* __restrict__ hl,
    const int* __restrict__ ls, const int* __restrict__ ld,
    const float* __restrict__ w1, const float* __restrict__ b1,
    const float* __restrict__ w2, const float* __restrict__ b2,
    float* __restrict__ out, int M)
{
    __shared__ float w1s[64 * 64];
    __shared__ float b1s[64];
    __shared__ float w2s[64];
    int tid = threadIdx.x;
#pragma unroll
    for (int i = 0; i < 16; ++i) w1s[tid + i * 256] = w1[tid + i * 256];
    if (tid < 64) { b1s[tid] = b1[tid]; w2s[tid] = w2[tid]; }
    __syncthreads();
    int m = blockIdx.x * 256 + tid;
    if (m >= M) return;
    float f[64];
    const float* hp = hd + (size_t)ls[m] * 32;
    const float* lp = hl + (size_t)ld[m] * 32;
#pragma unroll
    for (int c = 0; c < 32; ++c) { f[c] = hp[c]; f[32 + c] = lp[c]; }
    float o = b2[0];
    for (int j = 0; j < 64; ++j) {
        float hj = b1s[j];
#pragma unroll
        for (int k = 0; k < 64; ++k) hj += f[k] * w1s[k * 64 + j];
        hj = fmaxf(hj, 0.f);
        o += hj * w2s[j];
    }
    out[m] = o;
}

extern "C" void kernel_launch(void* const* d_in, const int* in_sizes, int n_in,
                              void* d_out, int out_size, void* d_ws, size_t ws_size,
                              hipStream_t stream)
{
    const float* x_d = (const float*)d_in[0];
    const float* x_l = (const float*)d_in[1];
    const int* node_id_d = (const int*)d_in[2];
    const int* node_id_l = (const int*)d_in[3];
    const int* edge_src = (const int*)d_in[4];
    const int* edge_dst = (const int*)d_in[5];
    const int* label_src = (const int*)d_in[6];
    const int* label_dst = (const int*)d_in[7];
    const float* emb_d = (const float*)d_in[8];
    const float* emb_l = (const float*)d_in[9];
    const float* lin_dw = (const float*)d_in[10];
    const float* lin_db = (const float*)d_in[11];
    const float* lin_lw = (const float*)d_in[12];
    const float* lin_lb = (const float*)d_in[13];
    const float* Ws[3] = {(const float*)d_in[14], (const float*)d_in[19], (const float*)d_in[24]};
    const float* Wd[3] = {(const float*)d_in[15], (const float*)d_in[20], (const float*)d_in[25]};
    const float* as_[3] = {(const float*)d_in[16], (const float*)d_in[21], (const float*)d_in[26]};
    const float* ad_[3] = {(const float*)d_in[17], (const float*)d_in[22], (const float*)d_in[27]};
    const float* bb[3] = {(const float*)d_in[18], (const float*)d_in[23], (const float*)d_in[28]};
    const float* pw = (const float*)d_in[29];
    const float* pb = (const float*)d_in[30];
    const float* fc1w = (const float*)d_in[31];
    const float* fc1b = (const float*)d_in[32];
    const float* fc2w = (const float*)d_in[33];
    const float* fc2b = (const float*)d_in[34];

    char* wsb = (char*)d_ws;
    size_t woff = 0;
    auto carve = [&](size_t bytes) -> void* {
        woff = (woff + 255) & ~(size_t)255;
        void* p = wsb + woff;
        woff += bytes;
        return p;
    };
    float* hdA = (float*)carve((size_t)ND * 128 * 4);
    float* hlA = (float*)carve((size_t)NL * 128 * 4);
    float* hdB = (float*)carve((size_t)ND * 128 * 4);
    float* hlB = (float*)carve((size_t)NL * 128 * 4);
    unsigned int* haggP = (unsigned int*)carve((size_t)NL * 2048 * 4);  // L3 reuses as zs3d/zs3l
    unsigned short* WtH = (unsigned short*)carve((size_t)2 * 2 * 2048 * 128 * 2);
    unsigned short* WtL = (unsigned short*)carve((size_t)2 * 2 * 2048 * 128 * 2);
    float* ssb0 = (float*)carve((size_t)ND * 16 * 4);
    float* sdb0 = (float*)carve((size_t)NL * 16 * 4);
    float* ssb1 = (float*)carve((size_t)NL * 16 * 4);
    float* sdb1 = (float*)carve((size_t)ND * 16 * 4);
    float* msl = (float*)carve((size_t)NL * 32 * 4);
    float* msd = (float*)carve((size_t)ND * 32 * 4);
    float* fw3 = (float*)carve((size_t)3 * 4 * 2048 * 4);
    int* degl = (int*)carve((size_t)(2 * (NL + ND)) * 4);
    int* degd = degl + NL;
    int* curl = degd + ND;
    int* curd = curl + NL;
    int* offl = (int*)carve((size_t)(NL + 1) * 4);
    int* offd = (int*)carve((size_t)(ND + 1) * 4);
    int* csrl = (int*)carve((size_t)NE * 4);
    int* csrd = (int*)carve((size_t)NE * 4);
    float* hdp = (float*)carve((size_t)ND * 32 * 4);
    float* hlp = (float*)carve((size_t)NL * 32 * 4);

    hipMemsetAsync(degl, 0, (size_t)2 * (NL + ND) * 4, stream);

    hist_kernel<<<(NE + 255) / 256, 256, 0, stream>>>(edge_src, edge_dst, degl, degd);
    scan2_kernel<<<2, 1024, 0, stream>>>(degl, offl, NL, degd, offd, ND);
    scatter_kernel<<<(NE + 255) / 256, 256, 0, stream>>>(edge_src, edge_dst, offl, offd, curl, curd, csrl, csrd);

    fold3_kernel<<<(3 * 8192 + 255) / 256, 256, 0, stream>>>(
        Ws[0], Wd[0], as_[0], ad_[0], Ws[1], Wd[1], as_[1], ad_[1],
        Ws[2], Wd[2], as_[2], ad_[2], fw3);
    wt2_kernel<<<(2 * 524288 + 255) / 256, 256, 0, stream>>>(Ws[0], Ws[1], WtH, WtL);

    inlin_kernel<<<dim3(2, 750), 256, 0, stream>>>(
        x_d, x_l, lin_dw, lin_lw, lin_db, lin_lb, emb_d, emb_l,
        node_id_d, node_id_l, hdA, hlA);

    float* hd_cur = hdA; float* hd_nxt = hdB;
    float* hl_cur = hlA; float* hl_nxt = hlB;

    const int grid_ms = ((NL + ND) * 16 + 255) / 256;
    // XCD-swizzled 4-way gemm2r grids: 32 blocks per group of 8 m-tiles
    const int gridNL = ((NL / 64 + 7) / 8) * 32;   // 250 tiles -> 1024 blocks
    const int gridND = ((ND / 64 + 7) / 8) * 32;   // 125 tiles -> 512 blocks

    // ---- layers 1-2: aggregate-then-project (split-bf16 MFMA, fused head-mean) ----
    for (int L = 0; L < 2; ++L) {
        const float* fw = fw3 + (size_t)L * 8192;
        const unsigned short* wtH = WtH + (size_t)L * 524288;
        const unsigned short* wtL = WtL + (size_t)L * 524288;

        score2both_kernel<<<ND / 16 + NL / 16, 256, 0, stream>>>(
            hd_cur, hl_cur, fw, ssb0, sdb1, sdb0, ssb1);
        ms_kernel<<<grid_ms, 256, 0, stream>>>(edge_src, edge_dst, ssb0, sdb0, ssb1, sdb1,
                                               offl, csrl, msl, offd, csrd, msd);

        // edge type 0: disease -> lncrna (dst = lncrna)
        hagg_kernel<<<NL / 2, 256, 0, stream>>>(hd_cur, ssb0, sdb0, msl, offl, csrl, edge_src, haggP);
        gemm2r_kernel<<<gridNL, 256, 0, stream>>>(haggP, wtH, wtL, bb[L], hl_nxt, NL);

        // edge type 1: lncrna -> disease (dst = disease)
        hagg_kernel<<<ND / 2, 256, 0, stream>>>(hl_cur, ssb1, sdb1, msd, offd, csrd, edge_dst, haggP);
        gemm2r_kernel<<<gridND, 256, 0, stream>>>(haggP,
                                                  wtH + (size_t)2048 * 128, wtL + (size_t)2048 * 128,
                                                  bb[L] + 2048, hd_nxt, ND);

        float* t;
        t = hd_cur; hd_cur = hd_nxt; hd_nxt = t;
        t = hl_cur; hl_cur = hl_nxt; hl_nxt = t;
    }

    // ---- layer 3: project-then-aggregate (fp32), merged dispatches ----
    {
        const float* fw = fw3 + 2 * 8192;
        float* zs3d = (float*)haggP;
        float* zs3l = (float*)haggP + (size_t)ND * 512;
        score2both_kernel<<<ND / 16 + NL / 16, 256, 0, stream>>>(
            hd_cur, hl_cur, fw, ssb0, sdb1, sdb0, ssb1);
        ms_kernel<<<grid_ms, 256, 0, stream>>>(edge_src, edge_dst, ssb0, sdb0, ssb1, sdb1,
                                               offl, csrl, msl, offd, csrd, msd);

        gemm3_kernel<<<dim3(512 / BN, 125 + 250), 256, 0, stream>>>(
            hd_cur, hl_cur, Ws[2], zs3d, zs3l);

        agg32both_kernel<<<NL + ND, 256, 0, stream>>>(
            zs3d, zs3l, ssb0, sdb0, msl, ssb1, sdb1, msd,
            offl, csrl, offd, csrd, edge_src, edge_dst,
            bb[2], pw, pb, hlp, hdp);
    }

    mlp_kernel<<<(NM + 255) / 256, 256, 0, stream>>>(hdp, hlp, label_src, label_dst,
                                                     fc1w, fc1b, fc2w, fc2b, (float*)d_out, NM);
}

// Round 20
// 751.725 us; speedup vs baseline: 1.0690x; 1.0120x over previous
//
#include <hip/hip_runtime.h>
#include <cstdint>
#include <cstddef>

#define ND 8000
#define NL 16000
#define NE 60000
#define NM 50000

#define BM 64
#define BN 64
#define BK 16

typedef __attribute__((ext_vector_type(8))) short bf16x8;
typedef __attribute__((ext_vector_type(4))) float f32x4;
typedef __attribute__((ext_vector_type(8))) unsigned int u32x8;

__device__ __forceinline__ unsigned short f2bf(float x) {
    unsigned int u = __float_as_uint(x);
    unsigned int r = (u + 0x7FFFu + ((u >> 16) & 1u)) >> 16;
    return (unsigned short)r;
}
__device__ __forceinline__ float bf2f(unsigned short b) {
    return __uint_as_float(((unsigned int)b) << 16);
}
__device__ __forceinline__ float lrelu(float x) {
    return x >= 0.f ? x : 0.2f * x;
}

// ---------------- merged layer-3 GEMM: zs3d = hd @ W[0], zs3l = hl @ W[1] --------------
__global__ __launch_bounds__(256) void gemm3_kernel(
    const float* __restrict__ hd, const float* __restrict__ hl,
    const float* __restrict__ W,   // [2,128,512]
    float* __restrict__ zs3d, float* __restrict__ zs3l)
{
    __shared__ float As[BK][BM + 4];
    __shared__ float Bs[BK][BN + 4];
    int mt = blockIdx.y;
    const float* A; const float* B; float* Cm;
    if (mt < 125) { A = hd; B = W; Cm = zs3d; }
    else { mt -= 125; A = hl; B = W + 128 * 512; Cm = zs3l; }
    const int tid = threadIdx.x;
    const int tx = tid & 15, ty = tid >> 4;
    const int bm = mt * BM, bn = blockIdx.x * BN;
    float acc[4][4] = {};
    for (int k0 = 0; k0 < 128; k0 += BK) {
#pragma unroll
        for (int i = 0; i < 4; ++i) {
            int idx = tid + i * 256;
            int ml = idx >> 4, kl = idx & 15;
            As[kl][ml] = A[(size_t)(bm + ml) * 128 + k0 + kl];
        }
#pragma unroll
        for (int i = 0; i < 4; ++i) {
            int idx = tid + i * 256;
            int kl = idx >> 6, nl = idx & 63;
            Bs[kl][nl] = B[(size_t)(k0 + kl) * 512 + bn + nl];
        }
        __syncthreads();
#pragma unroll
        for (int k = 0; k < BK; ++k) {
            float4 av = *(const float4*)&As[k][ty * 4];
            float4 bv = *(const float4*)&Bs[k][tx * 4];
            float a4[4] = {av.x, av.y, av.z, av.w};
            float b4[4] = {bv.x, bv.y, bv.z, bv.w};
#pragma unroll
            for (int i = 0; i < 4; ++i)
#pragma unroll
                for (int j = 0; j < 4; ++j)
                    acc[i][j] += a4[i] * b4[j];
        }
        __syncthreads();
    }
#pragma unroll
    for (int i = 0; i < 4; ++i) {
        int gm = bm + ty * 4 + i;
        int gn0 = bn + tx * 4;
        float4 v;
        float* vp = &v.x;
#pragma unroll
        for (int j = 0; j < 4; ++j) vp[j] = acc[i][j];
        *(float4*)&Cm[(size_t)gm * 512 + gn0] = v;
    }
}

// ---------------- fused input linears, 32-row tiles, register double-buffer ------------
__global__ __launch_bounds__(256) void inlin_kernel(
    const float* __restrict__ x_d, const float* __restrict__ x_l,
    const float* __restrict__ wd, const float* __restrict__ wl,
    const float* __restrict__ bd, const float* __restrict__ bl,
    const float* __restrict__ embd, const float* __restrict__ embl,
    const int* __restrict__ nidd, const int* __restrict__ nidl,
    float* __restrict__ hd, float* __restrict__ hl)
{
    __shared__ float As[BK][32 + 4];
    __shared__ float Bs[BK][BN + 4];
    int mt = blockIdx.y;
    const float* A; const float* B; const float* bias; const float* emb;
    const int* nid; float* out;
    int K;
    if (mt < 250) {
        A = x_d; B = wd; bias = bd; emb = embd; nid = nidd; out = hd; K = 412;
    } else {
        mt -= 250;
        A = x_l; B = wl; bias = bl; emb = embl; nid = nidl; out = hl; K = 240;
    }
    const int tid = threadIdx.x;
    const int tx = tid & 15, ty = tid >> 4;
    const int bm = mt * 32, bn = blockIdx.x * BN;

    const int aml0 = tid >> 4, akl0 = tid & 15;
    const int aml1 = (tid + 256) >> 4, akl1 = tid & 15;
    const int bkl = tid >> 6, bnl = tid & 63;

    float pa[2], pb[4];
    {
        int gk0 = akl0, gk1 = akl1;
        pa[0] = (gk0 < K) ? A[(size_t)(bm + aml0) * K + gk0] : 0.f;
        pa[1] = (gk1 < K) ? A[(size_t)(bm + aml1) * K + gk1] : 0.f;
#pragma unroll
        for (int i = 0; i < 4; ++i) {
            int gk = bkl + i * 4;
            pb[i] = (gk < K) ? B[(size_t)gk * 128 + bn + bnl] : 0.f;
        }
    }

    float acc[2][4] = {};
    for (int k0 = 0; k0 < K; k0 += BK) {
        As[akl0][aml0] = pa[0];
        As[akl1][aml1] = pa[1];
#pragma unroll
        for (int i = 0; i < 4; ++i)
            Bs[bkl + i * 4][bnl] = pb[i];
        __syncthreads();
        int kn = k0 + BK;
        if (kn < K) {
            int gk0 = kn + akl0, gk1 = kn + akl1;
            pa[0] = (gk0 < K) ? A[(size_t)(bm + aml0) * K + gk0] : 0.f;
            pa[1] = (gk1 < K) ? A[(size_t)(bm + aml1) * K + gk1] : 0.f;
#pragma unroll
            for (int i = 0; i < 4; ++i) {
                int gk = kn + bkl + i * 4;
                pb[i] = (gk < K) ? B[(size_t)gk * 128 + bn + bnl] : 0.f;
            }
        }
#pragma unroll
        for (int k = 0; k < BK; ++k) {
            float a0 = As[k][ty * 2];
            float a1 = As[k][ty * 2 + 1];
            float4 bv = *(const float4*)&Bs[k][tx * 4];
            float b4[4] = {bv.x, bv.y, bv.z, bv.w};
#pragma unroll
            for (int j = 0; j < 4; ++j) {
                acc[0][j] += a0 * b4[j];
                acc[1][j] += a1 * b4[j];
            }
        }
        __syncthreads();
    }
#pragma unroll
    for (int i = 0; i < 2; ++i) {
        int gm = bm + ty * 2 + i;
        int gn0 = bn + tx * 4;
        const float* ep = emb + (size_t)nid[gm] * 128 + gn0;
        float4 v;
        float* vp = &v.x;
#pragma unroll
        for (int j = 0; j < 4; ++j)
            vp[j] = acc[i][j] + bias[gn0 + j] + ep[j];
        *(float4*)&out[(size_t)gm * 128 + gn0] = v;
    }
}

// ---------------- W transpose + split-bf16 into MFMA-fragment tiling, BOTH layers ------
__global__ void wt2_kernel(const float* __restrict__ W0, const float* __restrict__ W1,
                           unsigned short* __restrict__ WtH, unsigned short* __restrict__ WtL)
{
    int gid = blockIdx.x * 256 + threadIdx.x;
    if (gid >= 2 * 2 * 128 * 2048) return;
    int l = gid >> 19;
    int rem0 = gid & 524287;
    int dir = rem0 >> 18;
    int rem = rem0 & 262143;
    int k = rem >> 11, n = rem & 2047;
    const float* W = l ? W1 : W0;
    float v = W[(size_t)dir * 262144 + (size_t)k * 2048 + n];
    unsigned short hb = f2bf(v);
    unsigned short lb = f2bf(v - bf2f(hb));
    int u = n >> 4;
    int lane = (n & 15) + 16 * ((k >> 3) & 3);
    size_t o = (size_t)l * 524288 + (size_t)dir * 262144 +
               ((size_t)u * 4 + (k >> 5)) * 512 + lane * 8 + (k & 7);
    WtH[o] = hb;
    WtL[o] = lb;
}

// ---------------- fused per-head projection + bias + relu + HEAD-MEAN (layers 1-2) ----
// 4-way column split, XCD-aware swizzle; manual 2-stage A prefetch across the h loop
// so next-h A loads (L2/HBM) overlap current-h B loads + MFMAs.
__global__ __launch_bounds__(256) void gemm2r_kernel(
    const unsigned int* __restrict__ haggP,
    const unsigned short* __restrict__ WtH, const unsigned short* __restrict__ WtL,
    const float* __restrict__ bias, float* __restrict__ out, int M)
{
    const int wave = threadIdx.x >> 6;
    const int lane = threadIdx.x & 63;
    const int i = blockIdx.x;
    const int cb = (i >> 3) & 3;             // column quarter
    const int mt = (i >> 5) * 8 + (i & 7);   // m-tile
    if (mt >= (M >> 6)) return;
    const int m0 = mt * 64 + wave * 16;
    const int t = m0 >> 4;
    const int row = lane & 15;
    const int quad = lane >> 4;

    f32x4 mean[2] = {};

    // prefetch A fragments for h = 0
    u32x8 pA[4];
#pragma unroll
    for (int kc = 0; kc < 4; ++kc)
        pA[kc] = *(const u32x8*)(haggP + (((size_t)t * 16 + 0) * 4 + kc) * 512 + lane * 8);

    for (int h = 0; h < 16; ++h) {
        // unpack current h's A
        bf16x8 aH[4], aL[4];
#pragma unroll
        for (int kc = 0; kc < 4; ++kc) {
#pragma unroll
            for (int ii = 0; ii < 8; ++ii) {
                aH[kc][ii] = (short)(pA[kc][ii] & 0xffffu);
                aL[kc][ii] = (short)(pA[kc][ii] >> 16);
            }
        }
        // prefetch next h's A while MFMAs below execute
        if (h < 15) {
#pragma unroll
            for (int kc = 0; kc < 4; ++kc)
                pA[kc] = *(const u32x8*)(haggP + (((size_t)t * 16 + h + 1) * 4 + kc) * 512 + lane * 8);
        }

        f32x4 accH[2], accL[2];
#pragma unroll
        for (int ctl = 0; ctl < 2; ++ctl) {
            float bv = bias[h * 128 + cb * 32 + ctl * 16 + row];
            accH[ctl] = (f32x4){bv, bv, bv, bv};
            accL[ctl] = (f32x4){0.f, 0.f, 0.f, 0.f};
        }
#pragma unroll
        for (int kc = 0; kc < 4; ++kc) {
#pragma unroll
            for (int ctl = 0; ctl < 2; ++ctl) {
                const int u = h * 8 + cb * 2 + ctl;
                const size_t boff = ((size_t)u * 4 + kc) * 512 + lane * 8;
                bf16x8 bH = *(const bf16x8*)(WtH + boff);
                bf16x8 bL = *(const bf16x8*)(WtL + boff);
                accH[ctl] = __builtin_amdgcn_mfma_f32_16x16x32_bf16(aH[kc], bH, accH[ctl], 0, 0, 0);
                accL[ctl] = __builtin_amdgcn_mfma_f32_16x16x32_bf16(aH[kc], bL, accL[ctl], 0, 0, 0);
                accL[ctl] = __builtin_amdgcn_mfma_f32_16x16x32_bf16(aL[kc], bH, accL[ctl], 0, 0, 0);
            }
        }
#pragma unroll
        for (int ctl = 0; ctl < 2; ++ctl)
#pragma unroll
            for (int r = 0; r < 4; ++r)
                mean[ctl][r] += fmaxf(accH[ctl][r] + accL[ctl][r], 0.f);
    }

#pragma unroll
    for (int ctl = 0; ctl < 2; ++ctl) {
        int c = cb * 32 + ctl * 16 + row;
#pragma unroll
        for (int r = 0; r < 4; ++r) {
            int gm = m0 + quad * 4 + r;
            out[(size_t)gm * 128 + c] = mean[ctl][r] * (1.f / 16.f);
        }
    }
}

// ---------------- fold for ALL 3 layers ------------------------------------------------
__global__ void fold3_kernel(
    const float* __restrict__ Ws1, const float* __restrict__ Wd1,
    const float* __restrict__ as1, const float* __restrict__ ad1,
    const float* __restrict__ Ws2, const float* __restrict__ Wd2,
    const float* __restrict__ as2, const float* __restrict__ ad2,
    const float* __restrict__ Ws3, const float* __restrict__ Wd3,
    const float* __restrict__ as3, const float* __restrict__ ad3,
    float* __restrict__ fw3)
{
    int gid = blockIdx.x * blockDim.x + threadIdx.x;
    if (gid >= 3 * 4 * 128 * 16) return;
    int l = gid / 8192, rem1 = gid % 8192;
    int f = rem1 / 2048, rem = rem1 % 2048;
    int k = rem >> 4, h = rem & 15;
    int Ntot = (l == 2) ? 512 : 2048;
    int C = Ntot >> 4;
    const float* W;
    const float* a;
    if (l == 0) { W = (f & 1) ? Wd1 : Ws1; a = (f & 1) ? ad1 : as1; }
    else if (l == 1) { W = (f & 1) ? Wd2 : Ws2; a = (f & 1) ? ad2 : as2; }
    else { W = (f & 1) ? Wd3 : Ws3; a = (f & 1) ? ad3 : as3; }
    if (f >= 2) { W += 128 * Ntot; a += 16 * C; }
    float s = 0.f;
    for (int c = 0; c < C; ++c) s += W[(size_t)k * Ntot + h * C + c] * a[h * C + c];
    fw3[gid] = s;
}

// ---------------- score2both: all four folded scores of a layer ------------------------
__global__ __launch_bounds__(256) void score2both_kernel(
    const float* __restrict__ Hd, const float* __restrict__ Hl,
    const float* __restrict__ fw,
    float* __restrict__ ssb0, float* __restrict__ sdb1,
    float* __restrict__ sdb0, float* __restrict__ ssb1)
{
    __shared__ float hs[16 * 128];
    __shared__ float wa[128 * 16];
    __shared__ float wb[128 * 16];
    int b = blockIdx.x;
    const float* Hf; const float* WfA; const float* WfB;
    float* outA; float* outB; int n0;
    if (b < ND / 16) {
        Hf = Hd; WfA = fw; WfB = fw + 3 * 2048; outA = ssb0; outB = sdb1; n0 = b * 16;
    } else {
        Hf = Hl; WfA = fw + 1 * 2048; WfB = fw + 2 * 2048; outA = sdb0; outB = ssb1;
        n0 = (b - ND / 16) * 16;
    }
    int tid = threadIdx.x;
#pragma unroll
    for (int i = 0; i < 8; ++i) {
        int idx = tid + i * 256;
        int nl = idx >> 7, k = idx & 127;
        hs[idx] = Hf[(size_t)(n0 + nl) * 128 + k];
        wa[idx] = WfA[idx];
        wb[idx] = WfB[idx];
    }
    __syncthreads();
    int nl = tid >> 4, h = tid & 15;
    float sa = 0.f, sb = 0.f;
    for (int k = 0; k < 128; ++k) {
        float hv = hs[nl * 128 + k];
        sa += hv * wa[k * 16 + h];
        sb += hv * wb[k * 16 + h];
    }
    int gn = n0 + nl;
    outA[gn * 16 + h] = sa;
    outB[gn * 16 + h] = sb;
}

// ---------------- per-(dst,head) online softmax max/sum, logits inline -----------------
__global__ void ms_kernel(
    const int* __restrict__ esrc, const int* __restrict__ edst,
    const float* __restrict__ ssb0, const float* __restrict__ sdb0,
    const float* __restrict__ ssb1, const float* __restrict__ sdb1,
    const int* __restrict__ offl, const int* __restrict__ csrl, float* __restrict__ msl,
    const int* __restrict__ offd, const int* __restrict__ csrd, float* __restrict__ msd)
{
    int t = blockIdx.x * 256 + threadIdx.x;
    const int* off; const int* csr; const int* srcidx;
    const float* ss; float sdv; float* ms; int d, h;
    if (t < NL * 16) {
        d = t >> 4; h = t & 15;
        off = offl; csr = csrl; srcidx = esrc; ss = ssb0;
        sdv = sdb0[d * 16 + h]; ms = msl;
    } else {
        t -= NL * 16;
        if (t >= ND * 16) return;
        d = t >> 4; h = t & 15;
        off = offd; csr = csrd; srcidx = edst; ss = ssb1;
        sdv = sdb1[d * 16 + h]; ms = msd;
    }
    int e0 = off[d], e1 = off[d + 1];
    float m = -1e30f, s = 0.f;
    for (int e = e0; e < e1; ++e) {
        int sn = srcidx[csr[e]];
        float a = lrelu(ss[sn * 16 + h] + sdv);
        if (a > m) { s = s * __expf(m - a) + 1.f; m = a; }
        else s += __expf(a - m);
    }
    ms[d * 32 + h] = m;
    ms[d * 32 + 16 + h] = s + 1e-16f;
}

// ---------------- CSR build ----------------
__global__ void hist_kernel(const int* __restrict__ esrc, const int* __restrict__ edst,
                            int* __restrict__ degl, int* __restrict__ degd)
{
    int e = blockIdx.x * blockDim.x + threadIdx.x;
    if (e >= NE) return;
    atomicAdd(&degl[edst[e]], 1);
    atomicAdd(&degd[esrc[e]], 1);
}

__global__ __launch_bounds__(1024) void scan2_kernel(
    const int* __restrict__ degA, int* __restrict__ offA, int nA,
    const int* __restrict__ degB, int* __restrict__ offB, int nB)
{
    __shared__ int ps[1024];
    const int* deg = blockIdx.x ? degB : degA;
    int* off = blockIdx.x ? offB : offA;
    int n = blockIdx.x ? nB : nA;
    int tid = threadIdx.x;
    int chunk = (n + 1023) >> 10;
    int start = tid * chunk, end = min(start + chunk, n);
    int p = 0;
    for (int i = start; i < end; ++i) p += deg[i];
    ps[tid] = p;
    __syncthreads();
    for (int o = 1; o < 1024; o <<= 1) {
        int v = (tid >= o) ? ps[tid - o] : 0;
        __syncthreads();
        ps[tid] += v;
        __syncthreads();
    }
    int run = ps[tid] - p;
    for (int i = start; i < end; ++i) { off[i] = run; run += deg[i]; }
    if (tid == 1023) off[n] = ps[1023];
}

__global__ void scatter_kernel(const int* __restrict__ esrc, const int* __restrict__ edst,
                               const int* __restrict__ offl, const int* __restrict__ offd,
                               int* __restrict__ curl, int* __restrict__ curd,
                               int* __restrict__ csrl, int* __restrict__ csrd)
{
    int e = blockIdx.x * blockDim.x + threadIdx.x;
    if (e >= NE) return;
    int dl = edst[e]; int p = atomicAdd(&curl[dl], 1); csrl[offl[dl] + p] = e;
    int dd = esrc[e]; int q = atomicAdd(&curd[dd], 1); csrd[offd[dd] + q] = e;
}

// ---------------- fused alpha + per-head aggregation -> packed fragment-tiled hagg -----
__global__ __launch_bounds__(256) void hagg_kernel(
    const float* __restrict__ hsrc,   // [n_src, 128]
    const float* __restrict__ ss,     // src scores [n_src, 16]
    const float* __restrict__ sd,     // dst scores [n_dst, 16]
    const float* __restrict__ ms,     // [n_dst, 32] (m | s)
    const int* __restrict__ off, const int* __restrict__ csr, const int* __restrict__ srcidx,
    unsigned int* __restrict__ haggP)
{
    __shared__ float alpha_s[2][8][17];
    __shared__ int src_s[2][8];
    const int d0 = blockIdx.x * 2;
    const int tid = threadIdx.x;

    const int half = tid >> 7;
    const int c = tid & 127;
    const int d = d0 + half;
    const int my_e0 = off[d];
    const int my_deg = off[d + 1] - my_e0;
    const int deg0 = off[d0 + 1] - off[d0];
    const int deg1 = off[d0 + 2] - off[d0 + 1];
    const int degmax = deg0 > deg1 ? deg0 : deg1;
    const int ntrip = (degmax + 7) >> 3;

    float acc[16];
#pragma unroll
    for (int h = 0; h < 16; ++h) acc[h] = 0.f;

    for (int trip = 0; trip < ntrip; ++trip) {
        int ce = trip * 8;
        {
            int ei = c >> 4, h = c & 15;
            if (ce + ei < my_deg) {
                int eid = csr[my_e0 + ce + ei];
                int sn = srcidx[eid];
                float a = lrelu(ss[sn * 16 + h] + sd[d * 16 + h]);
                alpha_s[half][ei][h] = __expf(a - ms[d * 32 + h]) / ms[d * 32 + 16 + h];
                if (h == 0) src_s[half][ei] = sn;
            }
        }
        __syncthreads();
        int nc = min(8, my_deg - ce);
        for (int ei = 0; ei < nc; ++ei) {
            float v = hsrc[(size_t)src_s[half][ei] * 128 + c];
#pragma unroll
            for (int h = 0; h < 16; ++h)
                acc[h] += alpha_s[half][ei][h] * v;
        }
        __syncthreads();
    }

    const int t = d >> 4;
    const int lane8 = ((d & 15) + 16 * ((c >> 3) & 3)) * 8 + (c & 7);
    const int kc = c >> 5;
#pragma unroll
    for (int h = 0; h < 16; ++h) {
        float v = acc[h];
        unsigned short hb = f2bf(v);
        unsigned short lb = f2bf(v - bf2f(hb));
        size_t idx = (((size_t)t * 16 + h) * 4 + kc) * 512 + lane8;
        haggP[idx] = (unsigned int)hb | ((unsigned int)lb << 16);
    }
}

// ---------------- layer 3 merged: alpha inline + gather + bias + relu + mean + penalty -
__global__ __launch_bounds__(256) void agg32both_kernel(
    const float* __restrict__ zs3d, const float* __restrict__ zs3l,
    const float* __restrict__ ssb0, const float* __restrict__ sdb0, const float* __restrict__ msl,
    const float* __restrict__ ssb1, const float* __restrict__ sdb1, const float* __restrict__ msd,
    const int* __restrict__ offl, const int* __restrict__ csrl,
    const int* __restrict__ offd, const int* __restrict__ csrd,
    const int* __restrict__ esrc, const int* __restrict__ edst,
    const float* __restrict__ bias512,
    const float* __restrict__ pw, const float* __restrict__ pb,
    float* __restrict__ hlp, float* __restrict__ hdp)
{
    __shared__ float alpha_s[16][17];
    __shared__ int src_s[16];
    __shared__ float lds_out[512];
    __shared__ float hrow[32];
    int d = blockIdx.x;
    const float* zs; const float* ss; const float* sd; const float* ms;
    const int* off; const int* csr; const int* srcidx;
    const float* bias; const float* pwt; const float* pbt; float* out;
    if (d < NL) {
        zs = zs3d; ss = ssb0; sd = sdb0; ms = msl;
        off = offl; csr = csrl; srcidx = esrc;
        bias = bias512; pwt = pw + 32; pbt = pb + 1; out = hlp;
    } else {
        d -= NL;
        zs = zs3l; ss = ssb1; sd = sdb1; ms = msd;
        off = offd; csr = csrd; srcidx = edst;
        bias = bias512 + 512; pwt = pw; pbt = pb; out = hdp;
    }
    const int tid = threadIdx.x;
    const int e0 = off[d], e1 = off[d + 1];

    float acc0 = 0.f, acc1 = 0.f;
    const int hsel = tid >> 4;

    for (int ce = e0; ce < e1; ce += 16) {
        int nc = min(16, e1 - ce);
        if (tid < nc * 16) {
            int ei = tid >> 4, h = tid & 15;
            int eid = csr[ce + ei];
            int sn = srcidx[eid];
            float a = lrelu(ss[sn * 16 + h] + sd[d * 16 + h]);
            alpha_s[ei][h] = __expf(a - ms[d * 32 + h]) / ms[d * 32 + 16 + h];
            if (h == 0) src_s[ei] = sn;
        }
        __syncthreads();
        for (int ei = 0; ei < nc; ++ei) {
            float a = alpha_s[ei][hsel];
            float2 v = *(const float2*)(zs + (size_t)src_s[ei] * 512 + tid * 2);
            acc0 += a * v.x;
            acc1 += a * v.y;
        }
        __syncthreads();
    }

    lds_out[tid * 2] = fmaxf(acc0 + bias[tid * 2], 0.f);
    lds_out[tid * 2 + 1] = fmaxf(acc1 + bias[tid * 2 + 1], 0.f);
    __syncthreads();
    if (tid < 32) {
        float s = 0.f;
#pragma unroll
        for (int hh = 0; hh < 16; ++hh) s += lds_out[hh * 32 + tid];
        hrow[tid] = s * (1.f / 16.f);
    }
    __syncthreads();
    if (tid < 32) {
        float t = pbt[0];
#pragma unroll
        for (int c = 0; c < 32; ++c) t += hrow[c] * pwt[c];
        out[(size_t)d * 32 + tid] = hrow[tid] * expf(t);
    }
}

// ---------------- final MLP on label edges ----------------
__global__ __launch_bounds__(256) void mlp_kernel(
    const float* __restrict__ hd, const float* __restrict__ hl,
    const int* __restrict__ ls, const int* __restrict__ ld,
    const float* __restrict__ w1, const float* __restrict__ b1,
    const float* __restrict__ w2, const float* __restrict__ b2,
    float* __restrict__ out, int M)
{
    __shared__ float w1s[64 * 64];
    __shared__ float b1s[64];
    __shared__ float w2s[64];
    int tid = threadIdx.x;
#pragma unroll
    for (int i = 0; i < 16; ++i) w1s[tid + i * 256] = w1[tid + i * 256];
    if (tid < 64) { b1s[tid] = b1[tid]; w2s[tid] = w2[tid]; }
    __syncthreads();
    int m = blockIdx.x * 256 + tid;
    if (m >= M) return;
    float f[64];
    const float* hp = hd + (size_t)ls[m] * 32;
    const float* lp = hl + (size_t)ld[m] * 32;
#pragma unroll
    for (int c = 0; c < 32; ++c) { f[c] = hp[c]; f[32 + c] = lp[c]; }
    float o = b2[0];
    for (int j = 0; j < 64; ++j) {
        float hj = b1s[j];
#pragma unroll
        for (int k = 0; k < 64; ++k) hj += f[k] * w1s[k * 64 + j];
        hj = fmaxf(hj, 0.f);
        o += hj * w2s[j];
    }
    out[m] = o;
}

extern "C" void kernel_launch(void* const* d_in, const int* in_sizes, int n_in,
                              void* d_out, int out_size, void* d_ws, size_t ws_size,
                              hipStream_t stream)
{
    const float* x_d = (const float*)d_in[0];
    const float* x_l = (const float*)d_in[1];
    const int* node_id_d = (const int*)d_in[2];
    const int* node_id_l = (const int*)d_in[3];
    const int* edge_src = (const int*)d_in[4];
    const int* edge_dst = (const int*)d_in[5];
    const int* label_src = (const int*)d_in[6];
    const int* label_dst = (const int*)d_in[7];
    const float* emb_d = (const float*)d_in[8];
    const float* emb_l = (const float*)d_in[9];
    const float* lin_dw = (const float*)d_in[10];
    const float* lin_db = (const float*)d_in[11];
    const float* lin_lw = (const float*)d_in[12];
    const float* lin_lb = (const float*)d_in[13];
    const float* Ws[3] = {(const float*)d_in[14], (const float*)d_in[19], (const float*)d_in[24]};
    const float* Wd[3] = {(const float*)d_in[15], (const float*)d_in[20], (const float*)d_in[25]};
    const float* as_[3] = {(const float*)d_in[16], (const float*)d_in[21], (const float*)d_in[26]};
    const float* ad_[3] = {(const float*)d_in[17], (const float*)d_in[22], (const float*)d_in[27]};
    const float* bb[3] = {(const float*)d_in[18], (const float*)d_in[23], (const float*)d_in[28]};
    const float* pw = (const float*)d_in[29];
    const float* pb = (const float*)d_in[30];
    const float* fc1w = (const float*)d_in[31];
    const float* fc1b = (const float*)d_in[32];
    const float* fc2w = (const float*)d_in[33];
    const float* fc2b = (const float*)d_in[34];

    char* wsb = (char*)d_ws;
    size_t woff = 0;
    auto carve = [&](size_t bytes) -> void* {
        woff = (woff + 255) & ~(size_t)255;
        void* p = wsb + woff;
        woff += bytes;
        return p;
    };
    float* hdA = (float*)carve((size_t)ND * 128 * 4);
    float* hlA = (float*)carve((size_t)NL * 128 * 4);
    float* hdB = (float*)carve((size_t)ND * 128 * 4);
    float* hlB = (float*)carve((size_t)NL * 128 * 4);
    unsigned int* haggP = (unsigned int*)carve((size_t)NL * 2048 * 4);  // L3 reuses as zs3d/zs3l
    unsigned short* WtH = (unsigned short*)carve((size_t)2 * 2 * 2048 * 128 * 2);
    unsigned short* WtL = (unsigned short*)carve((size_t)2 * 2 * 2048 * 128 * 2);
    float* ssb0 = (float*)carve((size_t)ND * 16 * 4);
    float* sdb0 = (float*)carve((size_t)NL * 16 * 4);
    float* ssb1 = (float*)carve((size_t)NL * 16 * 4);
    float* sdb1 = (float*)carve((size_t)ND * 16 * 4);
    float* msl = (float*)carve((size_t)NL * 32 * 4);
    float* msd = (float*)carve((size_t)ND * 32 * 4);
    float* fw3 = (float*)carve((size_t)3 * 4 * 2048 * 4);
    int* degl = (int*)carve((size_t)(2 * (NL + ND)) * 4);
    int* degd = degl + NL;
    int* curl = degd + ND;
    int* curd = curl + NL;
    int* offl = (int*)carve((size_t)(NL + 1) * 4);
    int* offd = (int*)carve((size_t)(ND + 1) * 4);
    int* csrl = (int*)carve((size_t)NE * 4);
    int* csrd = (int*)carve((size_t)NE * 4);
    float* hdp = (float*)carve((size_t)ND * 32 * 4);
    float* hlp = (float*)carve((size_t)NL * 32 * 4);

    hipMemsetAsync(degl, 0, (size_t)2 * (NL + ND) * 4, stream);

    hist_kernel<<<(NE + 255) / 256, 256, 0, stream>>>(edge_src, edge_dst, degl, degd);
    scan2_kernel<<<2, 1024, 0, stream>>>(degl, offl, NL, degd, offd, ND);
    scatter_kernel<<<(NE + 255) / 256, 256, 0, stream>>>(edge_src, edge_dst, offl, offd, curl, curd, csrl, csrd);

    fold3_kernel<<<(3 * 8192 + 255) / 256, 256, 0, stream>>>(
        Ws[0], Wd[0], as_[0], ad_[0], Ws[1], Wd[1], as_[1], ad_[1],
        Ws[2], Wd[2], as_[2], ad_[2], fw3);
    wt2_kernel<<<(2 * 524288 + 255) / 256, 256, 0, stream>>>(Ws[0], Ws[1], WtH, WtL);

    inlin_kernel<<<dim3(2, 750), 256, 0, stream>>>(
        x_d, x_l, lin_dw, lin_lw, lin_db, lin_lb, emb_d, emb_l,
        node_id_d, node_id_l, hdA, hlA);

    float* hd_cur = hdA; float* hd_nxt = hdB;
    float* hl_cur = hlA; float* hl_nxt = hlB;

    const int grid_ms = ((NL + ND) * 16 + 255) / 256;
    const int gridNL = ((NL / 64 + 7) / 8) * 32;   // 250 tiles -> 1024 blocks
    const int gridND = ((ND / 64 + 7) / 8) * 32;   // 125 tiles -> 512 blocks

    // ---- layers 1-2: aggregate-then-project (split-bf16 MFMA, fused head-mean) ----
    for (int L = 0; L < 2; ++L) {
        const float* fw = fw3 + (size_t)L * 8192;
        const unsigned short* wtH = WtH + (size_t)L * 524288;
        const unsigned short* wtL = WtL + (size_t)L * 524288;

        score2both_kernel<<<ND / 16 + NL / 16, 256, 0, stream>>>(
            hd_cur, hl_cur, fw, ssb0, sdb1, sdb0, ssb1);
        ms_kernel<<<grid_ms, 256, 0, stream>>>(edge_src, edge_dst, ssb0, sdb0, ssb1, sdb1,
                                               offl, csrl, msl, offd, csrd, msd);

        // edge type 0: disease -> lncrna (dst = lncrna)
        hagg_kernel<<<NL / 2, 256, 0, stream>>>(hd_cur, ssb0, sdb0, msl, offl, csrl, edge_src, haggP);
        gemm2r_kernel<<<gridNL, 256, 0, stream>>>(haggP, wtH, wtL, bb[L], hl_nxt, NL);

        // edge type 1: lncrna -> disease (dst = disease)
        hagg_kernel<<<ND / 2, 256, 0, stream>>>(hl_cur, ssb1, sdb1, msd, offd, csrd, edge_dst, haggP);
        gemm2r_kernel<<<gridND, 256, 0, stream>>>(haggP,
                                                  wtH + (size_t)2048 * 128, wtL + (size_t)2048 * 128,
                                                  bb[L] + 2048, hd_nxt, ND);

        float* t;
        t = hd_cur; hd_cur = hd_nxt; hd_nxt = t;
        t = hl_cur; hl_cur = hl_nxt; hl_nxt = t;
    }

    // ---- layer 3: project-then-aggregate (fp32), merged dispatches ----
    {
        const float* fw = fw3 + 2 * 8192;
        float* zs3d = (float*)haggP;
        float* zs3l = (float*)haggP + (size_t)ND * 512;
        score2both_kernel<<<ND / 16 + NL / 16, 256, 0, stream>>>(
            hd_cur, hl_cur, fw, ssb0, sdb1, sdb0, ssb1);
        ms_kernel<<<grid_ms, 256, 0, stream>>>(edge_src, edge_dst, ssb0, sdb0, ssb1, sdb1,
                                               offl, csrl, msl, offd, csrd, msd);

        gemm3_kernel<<<dim3(512 / BN, 125 + 250), 256, 0, stream>>>(
            hd_cur, hl_cur, Ws[2], zs3d, zs3l);

        agg32both_kernel<<<NL + ND, 256, 0, stream>>>(
            zs3d, zs3l, ssb0, sdb0, msl, ssb1, sdb1, msd,
            offl, csrl, offd, csrd, edge_src, edge_dst,
            bb[2], pw, pb, hlp, hdp);
    }

    mlp_kernel<<<(NM + 255) / 256, 256, 0, stream>>>(hdp, hlp, label_src, label_dst,
                                                     fc1w, fc1b, fc2w, fc2b, (float*)d_out, NM);
}